// Round 10
// baseline (2191.847 us; speedup 1.0000x reference)
//
#include <hip/hip_runtime.h>
#include <hip/hip_bf16.h>

#define N_NODES 50000
#define N_EDGES 800000
#define HDIM 100
#define ESTR 104   // e row stride (f16): 208B, 16B-aligned; cols 100..103 exact zero

typedef _Float16 half8_t __attribute__((ext_vector_type(8)));
typedef _Float16 half4_t __attribute__((ext_vector_type(4)));
typedef float f32x4_t __attribute__((ext_vector_type(4)));

// ---------------- weight fragment prep ----------------
// frag element ((t*ksteps + s)*64 + lane)*8 + i == B[s*32+(lane>>4)*8+i][t*16+(lane&15)]
struct FragDesc {
  const float* src; int stride; int K; int N; int outOff; int ksteps; int ntiles;
};
struct PrepArgs {
  FragDesc d[20];
  int prefix[21];
  int ndesc;
};

__global__ void k_prep_frags(PrepArgs args, _Float16* __restrict__ out) {
  int b = blockIdx.x;
  int di = 0;
  while (di + 1 < args.ndesc && b >= args.prefix[di + 1]) di++;
  FragDesc d = args.d[di];
  int local = b - args.prefix[di];
  int t = local / d.ksteps;
  int s = local % d.ksteps;
  int lane = threadIdx.x;            // 64 threads
  int col = t * 16 + (lane & 15);
  int kb = s * 32 + (lane >> 4) * 8;
  _Float16* o = out + d.outOff + (size_t)((t * d.ksteps + s) * 64 + lane) * 8;
  #pragma unroll
  for (int i = 0; i < 8; ++i) {
    int k = kb + i;
    float v = (k < d.K && col < d.N) ? d.src[(size_t)k * d.stride + col] : 0.0f;
    o[i] = (_Float16)v;
  }
}

// diagnostic: if workspace too small, encode ws_size (MB) into the output
__global__ void k_ws_probe(float* out, float mb) { out[0] = mb; }

// ---------------- CSR build (dst-sorted edge permutation) ----------------
__global__ void k_hist(const int* __restrict__ dst, int* __restrict__ cnt) {
  for (int e = blockIdx.x * blockDim.x + threadIdx.x; e < N_EDGES;
       e += gridDim.x * blockDim.x)
    atomicAdd(&cnt[dst[e]], 1);
}

// single-block exclusive scan: cnt -> rowptr[N+1], cursor[N].
// NOTE: cnt may alias cursor (cv read before overwrite; each n owned by one thread).
__global__ __launch_bounds__(1024) void k_scan(const int* cnt,
                                               int* rowptr,
                                               int* cursor) {
  __shared__ int part[1024];
  int t = threadIdx.x;
  const int CH = (N_NODES + 1023) / 1024;   // 49
  int base = t * CH;
  int s = 0;
  for (int i = 0; i < CH; ++i) {
    int n = base + i;
    if (n < N_NODES) s += cnt[n];
  }
  part[t] = s;
  __syncthreads();
  for (int off = 1; off < 1024; off <<= 1) {
    int v = 0;
    if (t >= off) v = part[t - off];
    __syncthreads();
    if (t >= off) part[t] += v;
    __syncthreads();
  }
  int run = (t == 0) ? 0 : part[t - 1];
  for (int i = 0; i < CH; ++i) {
    int n = base + i;
    if (n <= N_NODES) {
      rowptr[n] = run;
      if (n < N_NODES) {
        int cv = cnt[n];          // read BEFORE cursor write (alias-safe)
        cursor[n] = run;
        run += cv;
      }
    }
  }
}

__global__ void k_perm(const int* __restrict__ src, const int* __restrict__ dst,
                       int* __restrict__ cursor, int* __restrict__ perm,
                       int* __restrict__ srcS, int* __restrict__ dstS) {
  for (int e = blockIdx.x * blockDim.x + threadIdx.x; e < N_EDGES;
       e += gridDim.x * blockDim.x) {
    int d = dst[e];
    int pos = atomicAdd(&cursor[d], 1);
    perm[pos] = e;
    srcS[pos] = src[e];
    dstS[pos] = d;
  }
}

// ---------------- gather aggregation (no atomics) ----------------
// agg[n][j] = sum over in-edges of relu(h[src] + e_edge[j]).
// L0: e0 recomputed exactly in f32 from attr (8-dot, LDS-staged edge_w); attr via perm.
// !L0: e stored in pos order -> fully sequential reads.
template<bool L0>
__global__ __launch_bounds__(256) void k_agg(
    const int* __restrict__ rowptr, const int* __restrict__ perm,
    const int* __restrict__ srcS,
    const float* __restrict__ attr, const float* __restrict__ ew,
    const float* __restrict__ ebias,
    const _Float16* __restrict__ e,
    const float* __restrict__ h, float* __restrict__ agg) {
  __shared__ float EwL[800];
  __shared__ float ebL[128];
  int tid = threadIdx.x;
  if constexpr (L0) {
    for (int idx = tid; idx < 800; idx += 256) EwL[idx] = ew[idx];
    if (tid < 128) ebL[tid] = (tid < HDIM) ? ebias[tid] : 0.0f;
    __syncthreads();
  }
  int n = blockIdx.x * 2 + (tid >> 7);
  int j = tid & 127;
  if (n >= N_NODES || j >= HDIM) return;
  float acc = 0.0f;
  int p0 = rowptr[n], p1 = rowptr[n + 1];
  for (int pos = p0; pos < p1; ++pos) {
    int s = srcS[pos];
    float m;
    if constexpr (L0) {
      int eid = perm[pos];
      const float* ap = attr + (size_t)eid * 8;
      float e0 = ebL[j];
      #pragma unroll
      for (int k = 0; k < 8; ++k) e0 += ap[k] * EwL[k * HDIM + j];
      m = h[(size_t)s * HDIM + j] + e0;
    } else {
      m = h[(size_t)s * HDIM + j] + (float)e[(size_t)pos * ESTR + j];
    }
    acc += fmaxf(m, 0.0f);
  }
  agg[(size_t)n * HDIM + j] = acc;
}

// ---------------- small helpers ----------------
__device__ __forceinline__ half8_t h8_zero() {
  half8_t a;
  #pragma unroll
  for (int i = 0; i < 8; ++i) a[i] = (_Float16)0.0f;
  return a;
}

// XOR swizzle on 16B chunks inside a [16][128] f16 row-major tile (G4).
__device__ __forceinline__ int swz_idx(int r, int c) {
  int chunk = (c >> 3) ^ (r & 7);
  return r * 128 + chunk * 8 + (c & 7);
}

// A-fragment load from an f32 [rows][100] buffer. MODE 1: relu(v), 2: h+agg
template<int MODE>
__device__ __forceinline__ void load_a_node(const float* hp0,
                                            const float* ap0,
                                            int row, int lane, half8_t av[4]) {
  int g = lane >> 4;
  bool rv = (row < N_NODES);
  const float* hp = hp0 + (size_t)row * HDIM;
  const float* ap = ap0 + (size_t)row * HDIM;
  #pragma unroll
  for (int s = 0; s < 4; ++s) {
    int kb = s * 32 + g * 8;
    half8_t a = h8_zero();
    if (rv && kb < HDIM) {
      float f[8];
      #pragma unroll
      for (int i = 0; i < 8; ++i) f[i] = 0.0f;
      if (kb + 8 <= HDIM) {
        float4 v0 = *(const float4*)(hp + kb);
        float4 v1 = *(const float4*)(hp + kb + 4);
        f[0] = v0.x; f[1] = v0.y; f[2] = v0.z; f[3] = v0.w;
        f[4] = v1.x; f[5] = v1.y; f[6] = v1.z; f[7] = v1.w;
        if constexpr (MODE == 2) {
          float4 u0 = *(const float4*)(ap + kb);
          float4 u1 = *(const float4*)(ap + kb + 4);
          f[0] += u0.x; f[1] += u0.y; f[2] += u0.z; f[3] += u0.w;
          f[4] += u1.x; f[5] += u1.y; f[6] += u1.z; f[7] += u1.w;
        }
      } else {  // kb == 96: 4 valid elements
        float4 v0 = *(const float4*)(hp + kb);
        f[0] = v0.x; f[1] = v0.y; f[2] = v0.z; f[3] = v0.w;
        if constexpr (MODE == 2) {
          float4 u0 = *(const float4*)(ap + kb);
          f[0] += u0.x; f[1] += u0.y; f[2] += u0.z; f[3] += u0.w;
        }
      }
      #pragma unroll
      for (int i = 0; i < 8; ++i) {
        float v = f[i];
        if constexpr (MODE == 1) v = fmaxf(v, 0.0f);
        a[i] = (_Float16)v;
      }
    }
    av[s] = a;
  }
}

template<int NT, int KS>
__device__ __forceinline__ void mfma_tiles(const half8_t* av, const _Float16* __restrict__ fb,
                                           int lane, f32x4_t* acc) {
  #pragma unroll
  for (int t = 0; t < NT; ++t) {
    #pragma unroll
    for (int s = 0; s < KS; ++s) {
      half8_t bv = *(const half8_t*)(fb + (size_t)(((t * KS + s) * 64 + lane) << 3));
      acc[t] = __builtin_amdgcn_mfma_f32_16x16x32_f16(av[s], bv, acc[t], 0, 0, 0);
    }
  }
}

template<int KS>
__device__ __forceinline__ void lds_read_a(const _Float16* L, int lane, half8_t* av) {
  int r = lane & 15;
  int g = lane >> 4;
  #pragma unroll
  for (int s = 0; s < KS; ++s) {
    int kb = s * 32 + g * 8;
    av[s] = *(const half8_t*)&L[swz_idx(r, kb)];
  }
}

// ---------------- embeddings ----------------
__global__ void k_embed_h(const float* __restrict__ x, const float* __restrict__ w,
                          const float* __restrict__ bias, float* __restrict__ h) {
  int n = blockIdx.x;
  int j = threadIdx.x;
  if (j >= HDIM) return;
  float acc = bias[j];
  #pragma unroll
  for (int k = 0; k < 16; ++k) acc += x[n * 16 + k] * w[k * HDIM + j];
  h[(size_t)n * HDIM + j] = acc;
}

// ---------------- node-side kernels ----------------
// GINEConv MLP + BN partial stats. z aliases agg -> no __restrict__.
__global__ __launch_bounds__(256) void k_node_conv(
    const float* __restrict__ h, const float* agg,
    const _Float16* __restrict__ fb1, const _Float16* __restrict__ fb2,
    const float* __restrict__ b1, const float* __restrict__ b2,
    float* z, float* __restrict__ bn_sum, float* __restrict__ bn_sq) {
  __shared__ __align__(16) _Float16 lds[4][2048];
  int lane = threadIdx.x & 63;
  int wave = threadIdx.x >> 6;
  _Float16* L = lds[wave];
  int mbase = (blockIdx.x * 4 + wave) * 16;

  half8_t av[4];
  load_a_node<2>(h, agg, mbase + (lane & 15), lane, av);
  f32x4_t acc[7];
  #pragma unroll
  for (int t = 0; t < 7; ++t) acc[t] = (f32x4_t){0.f, 0.f, 0.f, 0.f};
  mfma_tiles<7, 4>(av, fb1, lane, acc);

  #pragma unroll
  for (int t = 0; t < 7; ++t) {
    int j = t * 16 + (lane & 15);
    float bias = (j < HDIM) ? b1[j] : 0.0f;
    #pragma unroll
    for (int q = 0; q < 4; ++q) {
      int r = (lane >> 4) * 4 + q;
      float v = fmaxf(acc[t][q] + bias, 0.0f);
      if (j >= HDIM) v = 0.0f;
      L[swz_idx(r, j)] = (_Float16)v;
    }
  }
  { int r = lane >> 2; int c0 = 112 + (lane & 3) * 4;
    #pragma unroll
    for (int i = 0; i < 4; ++i) L[swz_idx(r, c0 + i)] = (_Float16)0.0f;
  }
  __builtin_amdgcn_sched_barrier(0);

  half8_t av2[4];
  lds_read_a<4>(L, lane, av2);
  f32x4_t acc2[7];
  #pragma unroll
  for (int t = 0; t < 7; ++t) acc2[t] = (f32x4_t){0.f, 0.f, 0.f, 0.f};
  mfma_tiles<7, 4>(av2, fb2, lane, acc2);
  __builtin_amdgcn_sched_barrier(0);

  #pragma unroll
  for (int t = 0; t < 7; ++t) {
    int j = t * 16 + (lane & 15);
    float bias = (j < HDIM) ? b2[j] : 0.0f;
    float colsum = 0.0f, colsq = 0.0f;
    #pragma unroll
    for (int q = 0; q < 4; ++q) {
      int row = mbase + (lane >> 4) * 4 + q;
      float v = acc2[t][q] + bias;
      bool ok = (row < N_NODES) && (j < HDIM);
      if (ok) z[(size_t)row * HDIM + j] = v;
      float sv = ok ? v : 0.0f;
      colsum += sv; colsq += sv * sv;
    }
    colsum += __shfl_xor(colsum, 16);
    colsum += __shfl_xor(colsum, 32);
    colsq  += __shfl_xor(colsq, 16);
    colsq  += __shfl_xor(colsq, 32);
    if (lane < 16 && j < HDIM) {
      atomicAdd(&bn_sum[j], colsum);
      atomicAdd(&bn_sq[j], colsq);
    }
  }
}

__global__ void k_bn_final(const float* __restrict__ bn_sum, const float* __restrict__ bn_sq,
                           float* __restrict__ bn_mu, float* __restrict__ bn_rs) {
  int j = threadIdx.x;
  if (j >= HDIM) return;
  float mu = bn_sum[j] / (float)N_NODES;
  float var = bn_sq[j] / (float)N_NODES - mu * mu;
  bn_mu[j] = mu;
  bn_rs[j] = rsqrtf(var + 1e-5f);
}

// fused h-update + PQt GEMM
__global__ __launch_bounds__(256) void k_h_pq(
    float* h, const float* z,
    const float* __restrict__ bn_mu, const float* __restrict__ bn_rs,
    const float* __restrict__ gamma, const float* __restrict__ beta,
    const _Float16* __restrict__ fb, _Float16* __restrict__ PQt) {
  int lane = threadIdx.x & 63;
  int wave = threadIdx.x >> 6;
  int c = lane & 15, g = lane >> 4;
  int mbase = (blockIdx.x * 4 + wave) * 16;
  int row = mbase + c;
  bool rv = row < N_NODES;
  float* hp = h + (size_t)row * HDIM;
  const float* zp = z + (size_t)row * HDIM;

  half8_t av[4];
  #pragma unroll
  for (int s = 0; s < 4; ++s) {
    int kb = s * 32 + g * 8;
    half8_t a = h8_zero();
    if (rv && kb < HDIM) {
      int lim = (kb + 8 <= HDIM) ? 8 : 4;
      float zf[8], hf[8], mu[8], rs[8], ga[8], be[8];
      { float4 v = *(const float4*)(zp + kb);
        zf[0]=v.x; zf[1]=v.y; zf[2]=v.z; zf[3]=v.w; }
      { float4 v = *(const float4*)(hp + kb);
        hf[0]=v.x; hf[1]=v.y; hf[2]=v.z; hf[3]=v.w; }
      { float4 v = *(const float4*)(bn_mu + kb);
        mu[0]=v.x; mu[1]=v.y; mu[2]=v.z; mu[3]=v.w; }
      { float4 v = *(const float4*)(bn_rs + kb);
        rs[0]=v.x; rs[1]=v.y; rs[2]=v.z; rs[3]=v.w; }
      { float4 v = *(const float4*)(gamma + kb);
        ga[0]=v.x; ga[1]=v.y; ga[2]=v.z; ga[3]=v.w; }
      { float4 v = *(const float4*)(beta + kb);
        be[0]=v.x; be[1]=v.y; be[2]=v.z; be[3]=v.w; }
      if (lim == 8) {
        { float4 v = *(const float4*)(zp + kb + 4);
          zf[4]=v.x; zf[5]=v.y; zf[6]=v.z; zf[7]=v.w; }
        { float4 v = *(const float4*)(hp + kb + 4);
          hf[4]=v.x; hf[5]=v.y; hf[6]=v.z; hf[7]=v.w; }
        { float4 v = *(const float4*)(bn_mu + kb + 4);
          mu[4]=v.x; mu[5]=v.y; mu[6]=v.z; mu[7]=v.w; }
        { float4 v = *(const float4*)(bn_rs + kb + 4);
          rs[4]=v.x; rs[5]=v.y; rs[6]=v.z; rs[7]=v.w; }
        { float4 v = *(const float4*)(gamma + kb + 4);
          ga[4]=v.x; ga[5]=v.y; ga[6]=v.z; ga[7]=v.w; }
        { float4 v = *(const float4*)(beta + kb + 4);
          be[4]=v.x; be[5]=v.y; be[6]=v.z; be[7]=v.w; }
      }
      float hn[8];
      #pragma unroll
      for (int i = 0; i < 8; ++i) hn[i] = 0.0f;
      for (int i = 0; i < 8; ++i) {
        if (i < lim) {
          float zn = (zf[i] - mu[i]) * rs[i] * ga[i] + be[i];
          hn[i] = 0.5f * (hf[i] + fmaxf(zn, 0.0f));
          a[i] = (_Float16)hn[i];
        }
      }
      { float4 v; v.x=hn[0]; v.y=hn[1]; v.z=hn[2]; v.w=hn[3];
        *(float4*)(hp + kb) = v; }
      if (lim == 8) {
        float4 v; v.x=hn[4]; v.y=hn[5]; v.z=hn[6]; v.w=hn[7];
        *(float4*)(hp + kb + 4) = v;
      }
    }
    av[s] = a;
  }

  f32x4_t acc[14];
  #pragma unroll
  for (int t = 0; t < 14; ++t) acc[t] = (f32x4_t){0.f, 0.f, 0.f, 0.f};
  mfma_tiles<14, 4>(av, fb, lane, acc);
  #pragma unroll
  for (int q = 0; q < 4; ++q) {
    int orow = mbase + (lane >> 4) * 4 + q;
    if (orow >= N_NODES) continue;
    half8_t hp8, hq8;
    #pragma unroll
    for (int t = 0; t < 8; ++t) {
      hp8[t] = (t < 7) ? (_Float16)acc[t][q] : (_Float16)0.0f;
      hq8[t] = (t < 7) ? (_Float16)acc[7 + t][q] : (_Float16)0.0f;
    }
    *(half8_t*)(PQt + (size_t)orow * 256 + c * 8) = hp8;
    *(half8_t*)(PQt + (size_t)orow * 256 + 128 + c * 8) = hq8;
  }
}

// RS' GEMM (reads h, relu'd): RS' [node][128]: R slot c*4+t, S slot 64+c*4+t
__global__ __launch_bounds__(256) void k_node_rs(const float* __restrict__ h,
                                                 const _Float16* __restrict__ fb,
                                                 _Float16* __restrict__ out) {
  int lane = threadIdx.x & 63;
  int wave = threadIdx.x >> 6;
  int c = lane & 15;
  int mbase = (blockIdx.x * 4 + wave) * 16;
  half8_t av[4];
  load_a_node<1>(h, h, mbase + c, lane, av);
  f32x4_t acc[8];
  #pragma unroll
  for (int t = 0; t < 8; ++t) acc[t] = (f32x4_t){0.f, 0.f, 0.f, 0.f};
  mfma_tiles<8, 4>(av, fb, lane, acc);
  #pragma unroll
  for (int q = 0; q < 4; ++q) {
    int row = mbase + (lane >> 4) * 4 + q;
    if (row >= N_NODES) continue;
    half4_t hr, hs;
    #pragma unroll
    for (int t = 0; t < 4; ++t) {
      hr[t] = (_Float16)acc[t][q];
      hs[t] = (_Float16)acc[4 + t][q];
    }
    *(half4_t*)(out + (size_t)row * 128 + c * 4) = hr;
    *(half4_t*)(out + (size_t)row * 128 + 64 + c * 4) = hs;
  }
}

// ---------------- layer-0 edge kernel (pos-ordered; e0 never in HBM) ----------------
// Occupancy-first: __launch_bounds__(256,8) caps VGPR at 64 -> 32 waves/CU.
// P/Q gathered AFTER stage-1 MFMA (latency hidden across waves, not in-wave regs).
__global__ __launch_bounds__(256, 8) void k_edge0(
    const float* __restrict__ attr,
    const _Float16* __restrict__ PQ,
    const int* __restrict__ srcS, const int* __restrict__ dstS,
    const int* __restrict__ perm,
    const float* __restrict__ ew, const float* __restrict__ ebias,
    const _Float16* __restrict__ fbW1c, const _Float16* __restrict__ fbW2,
    const float* __restrict__ b1, const float* __restrict__ b2,
    _Float16* __restrict__ e) {
  __shared__ __align__(16) _Float16 lds[4][2048];
  __shared__ float EwL[800];
  __shared__ float ebL[112];
  int tid = threadIdx.x;
  for (int idx = tid; idx < 800; idx += 256) EwL[idx] = ew[idx];
  if (tid < 112) ebL[tid] = (tid < HDIM) ? ebias[tid] : 0.0f;
  __syncthreads();

  int lane = tid & 63;
  int wave = tid >> 6;
  _Float16* L = lds[wave];
  int mbase = (blockIdx.x * 4 + wave) * 16;
  int c = lane & 15, g = lane >> 4;

  int sn[4], dn[4], pv[4];
  #pragma unroll
  for (int q = 0; q < 4; ++q) {
    int row = mbase + g * 4 + q;
    sn[q] = srcS[row]; dn[q] = dstS[row]; pv[q] = perm[row];
  }

  // attr rows (gathered via perm)
  float af[4][8];
  #pragma unroll
  for (int q = 0; q < 4; ++q) {
    const float* ap = attr + (size_t)pv[q] * 8;
    float4 a0 = *(const float4*)ap;
    float4 a1 = *(const float4*)(ap + 4);
    af[q][0] = a0.x; af[q][1] = a0.y; af[q][2] = a0.z; af[q][3] = a0.w;
    af[q][4] = a1.x; af[q][5] = a1.y; af[q][6] = a1.z; af[q][7] = a1.w;
  }

  // e0 in f32 (same FMA order as original embed_e); carry f16 bits (14 VGPR)
  _Float16 e0h[7][4];
  #pragma unroll
  for (int t = 0; t < 7; ++t) {
    int j = t * 16 + c;
    #pragma unroll
    for (int q = 0; q < 4; ++q) {
      float v = 0.0f;
      if (j < HDIM) {
        v = ebL[j];
        #pragma unroll
        for (int k = 0; k < 8; ++k) v += af[q][k] * EwL[k * HDIM + j];
      }
      _Float16 vh = (_Float16)v;
      e0h[t][q] = vh;
      L[swz_idx(g * 4 + q, j)] = vh;
    }
  }
  { int r = lane >> 2; int c0 = 112 + (lane & 3) * 4;
    #pragma unroll
    for (int i = 0; i < 4; ++i) L[swz_idx(r, c0 + i)] = (_Float16)0.0f;
  }
  __builtin_amdgcn_sched_barrier(0);

  half8_t av[4];
  lds_read_a<4>(L, lane, av);
  __builtin_amdgcn_sched_barrier(0);
  f32x4_t acc[7];
  #pragma unroll
  for (int t = 0; t < 7; ++t) acc[t] = (f32x4_t){0.f, 0.f, 0.f, 0.f};
  mfma_tiles<7, 4>(av, fbW1c, lane, acc);
  __builtin_amdgcn_sched_barrier(0);

  // P/Q gathers AFTER stage-1 MFMA (frees 32 VGPR during the MFMA cluster)
  half8_t Pf[4], Qf[4];
  #pragma unroll
  for (int q = 0; q < 4; ++q) {
    Pf[q] = *(const half8_t*)(PQ + (size_t)sn[q] * 256 + c * 8);
    Qf[q] = *(const half8_t*)(PQ + (size_t)dn[q] * 256 + 128 + c * 8);
  }

  #pragma unroll
  for (int t = 0; t < 7; ++t) {
    int j = t * 16 + c;
    float bias = (j < HDIM) ? b1[j] : 0.0f;
    #pragma unroll
    for (int q = 0; q < 4; ++q) {
      int r = g * 4 + q;
      float v = 0.0f;
      if (j < HDIM)
        v = fmaxf(acc[t][q] + bias + (float)Pf[q][t] + (float)Qf[q][t], 0.0f);
      L[swz_idx(r, j)] = (_Float16)v;
    }
  }
  __builtin_amdgcn_sched_barrier(0);

  half8_t av2[4];
  lds_read_a<4>(L, lane, av2);
  f32x4_t acc2[7];
  #pragma unroll
  for (int t = 0; t < 7; ++t) acc2[t] = (f32x4_t){0.f, 0.f, 0.f, 0.f};
  mfma_tiles<7, 4>(av2, fbW2, lane, acc2);
  __builtin_amdgcn_sched_barrier(0);

  #pragma unroll
  for (int t = 0; t < 7; ++t) {
    int j = t * 16 + c;
    float b2v = (j < HDIM) ? b2[j] : 0.0f;
    #pragma unroll
    for (int q = 0; q < 4; ++q) {
      int row = mbase + g * 4 + q;
      float eold = (float)e0h[t][q];
      float enew = eold + 0.5f * (acc2[t][q] + b2v);
      if (j < ESTR)
        e[(size_t)row * ESTR + j] = (j < HDIM) ? (_Float16)enew : (_Float16)0.0f;
    }
  }
}

// ---------------- layer-1 edge kernel + fused classifier (pos-ordered) ----------------
// Occupancy-first: __launch_bounds__(256,8) caps VGPR at 64 -> 32 waves/CU.
__global__ __launch_bounds__(256, 8) void k_edge1(
    const _Float16* __restrict__ e,
    const _Float16* __restrict__ PQ, const _Float16* __restrict__ RS,
    const int* __restrict__ srcS, const int* __restrict__ dstS,
    const int* __restrict__ perm,
    const _Float16* __restrict__ fbW1c, const _Float16* __restrict__ fbW2,
    const float* __restrict__ b1, const float* __restrict__ b2,
    const _Float16* __restrict__ fbC, const _Float16* __restrict__ fbM2,
    const _Float16* __restrict__ fbM3,
    const float* __restrict__ mb1, const float* __restrict__ mb2,
    const float* __restrict__ mb3, float* __restrict__ out) {
  __shared__ __align__(16) _Float16 lds[4][2048];
  int lane = threadIdx.x & 63;
  int wave = threadIdx.x >> 6;
  _Float16* L = lds[wave];
  int mbase = (blockIdx.x * 4 + wave) * 16;
  int c = lane & 15, g = lane >> 4;

  // e A-loads issued first (streaming, independent of indices)
  half8_t av[4];
  {
    const _Float16* ep = e + (size_t)(mbase + c) * ESTR;
    #pragma unroll
    for (int s = 0; s < 3; ++s)
      av[s] = *(const half8_t*)(ep + s * 32 + g * 8);
    av[3] = (g == 0) ? *(const half8_t*)(ep + 96) : h8_zero();
  }

  int sn[4], dn[4];
  #pragma unroll
  for (int q = 0; q < 4; ++q) {
    int row = mbase + g * 4 + q;
    sn[q] = srcS[row]; dn[q] = dstS[row];
  }

  f32x4_t acc[7];
  #pragma unroll
  for (int t = 0; t < 7; ++t) acc[t] = (f32x4_t){0.f, 0.f, 0.f, 0.f};
  mfma_tiles<7, 4>(av, fbW1c, lane, acc);
  __builtin_amdgcn_sched_barrier(0);

  // P/Q gathers AFTER stage-1 MFMA (frees 32 VGPR during the MFMA cluster;
  // latency hidden by the extra resident waves, not by in-wave hoisting)
  half8_t Pf[4], Qf[4];
  #pragma unroll
  for (int q = 0; q < 4; ++q) {
    Pf[q] = *(const half8_t*)(PQ + (size_t)sn[q] * 256 + c * 8);
    Qf[q] = *(const half8_t*)(PQ + (size_t)dn[q] * 256 + 128 + c * 8);
  }

  #pragma unroll
  for (int t = 0; t < 7; ++t) {
    int j = t * 16 + c;
    float bias = (j < HDIM) ? b1[j] : 0.0f;
    #pragma unroll
    for (int q = 0; q < 4; ++q) {
      int r = g * 4 + q;
      float v = 0.0f;
      if (j < HDIM)
        v = fmaxf(acc[t][q] + bias + (float)Pf[q][t] + (float)Qf[q][t], 0.0f);
      L[swz_idx(r, j)] = (_Float16)v;
    }
  }
  { int r = lane >> 2; int c0 = 112 + (lane & 3) * 4;
    #pragma unroll
    for (int i = 0; i < 4; ++i) L[swz_idx(r, c0 + i)] = (_Float16)0.0f;
  }
  __builtin_amdgcn_sched_barrier(0);

  half8_t av2[4];
  lds_read_a<4>(L, lane, av2);
  f32x4_t acc2[7];
  #pragma unroll
  for (int t = 0; t < 7; ++t) acc2[t] = (f32x4_t){0.f, 0.f, 0.f, 0.f};
  mfma_tiles<7, 4>(av2, fbW2, lane, acc2);
  __builtin_amdgcn_sched_barrier(0);

  // R/S gathers for the classifier
  half4_t Rf[4], Sf[4];
  #pragma unroll
  for (int q = 0; q < 4; ++q) {
    Rf[q] = *(const half4_t*)(RS + (size_t)sn[q] * 128 + c * 4);
    Sf[q] = *(const half4_t*)(RS + (size_t)dn[q] * 128 + 64 + c * 4);
  }

  // epilogue 2: e2 -> LDS; eold via global re-read (L2-hot from stage 1)
  #pragma unroll
  for (int t = 0; t < 7; ++t) {
    int j = t * 16 + c;
    float bias = (j < HDIM) ? b2[j] : 0.0f;
    #pragma unroll
    for (int q = 0; q < 4; ++q) {
      int row = mbase + g * 4 + q;
      float v = 0.0f;
      if (j < HDIM) {
        float eold = (float)e[(size_t)row * ESTR + j];
        v = eold + 0.5f * (acc2[t][q] + bias);
      }
      int r = g * 4 + q;
      L[swz_idx(r, j)] = (_Float16)v;
    }
  }
  __builtin_amdgcn_sched_barrier(0);

  // classifier stage 1: t1 = relu(e2@C + R + S + mb1), 50 outs
  half8_t av3[4];
  lds_read_a<4>(L, lane, av3);
  f32x4_t acc3[4];
  #pragma unroll
  for (int t = 0; t < 4; ++t) acc3[t] = (f32x4_t){0.f, 0.f, 0.f, 0.f};
  mfma_tiles<4, 4>(av3, fbC, lane, acc3);
  __builtin_amdgcn_sched_barrier(0);
  #pragma unroll
  for (int t = 0; t < 4; ++t) {
    int j = t * 16 + c;
    float bias = (j < 50) ? mb1[j] : 0.0f;
    #pragma unroll
    for (int q = 0; q < 4; ++q) {
      float v = 0.0f;
      if (j < 50)
        v = fmaxf(acc3[t][q] + bias + (float)Rf[q][t] + (float)Sf[q][t], 0.0f);
      int r = g * 4 + q;
      L[swz_idx(r, j)] = (_Float16)v;
    }
  }
  __builtin_amdgcn_sched_barrier(0);
  // classifier stage 2: t2 = relu(t1@M2 + mb2), 25 outs
  half8_t av4[2];
  lds_read_a<2>(L, lane, av4);
  f32x4_t acc4[2];
  #pragma unroll
  for (int t = 0; t < 2; ++t) acc4[t] = (f32x4_t){0.f, 0.f, 0.f, 0.f};
  mfma_tiles<2, 2>(av4, fbM2, lane, acc4);
  __builtin_amdgcn_sched_barrier(0);
  #pragma unroll
  for (int t = 0; t < 2; ++t) {
    int j = t * 16 + c;
    float bias = (j < 25) ? mb2[j] : 0.0f;
    #pragma unroll
    for (int q = 0; q < 4; ++q) {
      float v = (j < 25) ? fmaxf(acc4[t][q] + bias, 0.0f) : 0.0f;
      int r = g * 4 + q;
      L[swz_idx(r, j)] = (_Float16)v;
    }
  }
  __builtin_amdgcn_sched_barrier(0);
  // classifier stage 3: out = t2@M3 + mb3 (scattered to original edge ids)
  half8_t av5[1];
  lds_read_a<1>(L, lane, av5);
  f32x4_t acc5 = (f32x4_t){0.f, 0.f, 0.f, 0.f};
  {
    half8_t bv = *(const half8_t*)(fbM3 + (size_t)(lane << 3));
    acc5 = __builtin_amdgcn_mfma_f32_16x16x32_f16(av5[0], bv, acc5, 0, 0, 0);
  }
  if (c < 2) {
    float bias = mb3[c];
    #pragma unroll
    for (int q = 0; q < 4; ++q) {
      int row = mbase + g * 4 + q;
      out[(size_t)perm[row] * 2 + c] = acc5[q] + bias;
    }
  }
}

// ---------------- host launch ----------------
extern "C" void kernel_launch(void* const* d_in, const int* in_sizes, int n_in,
                              void* d_out, int out_size, void* d_ws, size_t ws_size,
                              hipStream_t stream) {
  const float* x        = (const float*)d_in[0];
  const int*   ei       = (const int*)  d_in[1];
  const float* eattr    = (const float*)d_in[2];
  const float* node_w   = (const float*)d_in[3];
  const float* node_b   = (const float*)d_in[4];
  const float* edge_w   = (const float*)d_in[5];
  const float* edge_b   = (const float*)d_in[6];
  const float* conv_w1  = (const float*)d_in[7];
  const float* conv_b1  = (const float*)d_in[8];
  const float* conv_w2  = (const float*)d_in[9];
  const float* conv_b2  = (const float*)d_in[10];
  const float* bn_gamma = (const float*)d_in[11];
  const float* bn_beta  = (const float*)d_in[12];
  const float* emlp_w1  = (const float*)d_in[13];
  const float* emlp_b1  = (const float*)d_in[14];
  const float* emlp_w2  = (const float*)d_in[15];
  const float* emlp_b2  = (const float*)d_in[16];
  const float* mlp_w1   = (const float*)d_in[17];
  const float* mlp_b1   = (const float*)d_in[18];
  const float* mlp_w2   = (const float*)d_in[19];
  const float* mlp_b2   = (const float*)d_in[20];
  const float* mlp_w3   = (const float*)d_in[21];
  const float* mlp_b3   = (const float*)d_in[22];
  const int* src = ei;
  const int* dst = ei + N_EDGES;

  char* ws = (char*)d_ws;
  size_t off = 0;
  auto alloc = [&](size_t bytes) -> void* {
    void* p = ws + off;
    off += (bytes + 255) & ~(size_t)255;
    return p;
  };
  _Float16* e    = (_Float16*)alloc((size_t)N_EDGES * ESTR * 2);   // 166.4 MB (pos order)
  float* h       = (float*)alloc((size_t)N_NODES * HDIM * 4);      //  20 MB
  float* agg     = (float*)alloc((size_t)N_NODES * HDIM * 4);      //  20 MB (z, RSt alias)
  _Float16* PQt  = (_Float16*)alloc((size_t)N_NODES * 256 * 2);    //  25.6 MB
  int* cursor    = (int*)alloc((size_t)N_NODES * 4);               //  0.2 MB (doubles as hist)
  int* rowptr    = (int*)alloc((size_t)(N_NODES + 1) * 4);         //  0.2 MB
  int* perm      = (int*)alloc((size_t)N_EDGES * 4);               //  3.2 MB
  int* srcS      = (int*)alloc((size_t)N_EDGES * 4);               //  3.2 MB
  int* dstS      = (int*)alloc((size_t)N_EDGES * 4);               //  3.2 MB
  float* bn_sum  = (float*)alloc(512);
  float* bn_sq   = (float*)alloc(512);
  float* bn_mu   = (float*)alloc(512);
  float* bn_rs   = (float*)alloc(512);
  _Float16* frags = (_Float16*)alloc(200000 * 2);                  //  0.4 MB
  float* z = agg;                 // alias: conv reads agg rows before writing same z rows
  _Float16* RSt = (_Float16*)agg; // alias: written at i==1 after z is dead

  if (off > ws_size) {
    k_ws_probe<<<1, 1, 0, stream>>>((float*)d_out, (float)(ws_size >> 20));
    return;
  }

  // fragment descriptor table
  PrepArgs pa;
  int nd = 0, tilesum = 0, fo = 0;
  auto add = [&](const float* sp, int stride, int K, int Ncols, int ksteps, int ntiles) -> int {
    pa.d[nd] = FragDesc{sp, stride, K, Ncols, fo, ksteps, ntiles};
    pa.prefix[nd] = tilesum;
    tilesum += ksteps * ntiles;
    ++nd;
    int ret = fo;
    fo += ksteps * ntiles * 512;
    return ret;
  };
  int offConvW1[2], offConvW2[2], offPQ[2], offW1c[2], offW2e[2];
  for (int i = 0; i < 2; ++i) {
    offConvW1[i] = add(conv_w1 + i * 10000, 100, 100, 100, 4, 7);
    offConvW2[i] = add(conv_w2 + i * 10000, 100, 100, 100, 4, 7);
    offPQ[i]     = add(emlp_w1 + i * 30000,         100, 100, 100, 4, 7);  // W1a (P)
                   add(emlp_w1 + i * 30000 + 10000, 100, 100, 100, 4, 7);  // W1b (Q), contiguous
    offW1c[i]    = add(emlp_w1 + i * 30000 + 20000, 100, 100, 100, 4, 7);
    offW2e[i]    = add(emlp_w2 + i * 10000, 100, 100, 100, 4, 7);
  }
  int offRS = add(mlp_w1,         50, 100, 50, 4, 4);   // R
              add(mlp_w1 + 5000,  50, 100, 50, 4, 4);   // S, contiguous
  int offC  = add(mlp_w1 + 10000, 50, 100, 50, 4, 4);
  int offM2 = add(mlp_w2, 25, 50, 25, 2, 2);
  int offM3 = add(mlp_w3, 2, 25, 2, 1, 1);
  pa.prefix[nd] = tilesum;
  pa.ndesc = nd;

  // CSR build (dst layer-invariant: one sort serves both layers)
  hipMemsetAsync(cursor, 0, (size_t)N_NODES * 4, stream);
  k_hist<<<2048, 256, 0, stream>>>(dst, cursor);
  k_scan<<<1, 1024, 0, stream>>>(cursor, rowptr, cursor);
  k_perm<<<2048, 256, 0, stream>>>(src, dst, cursor, perm, srcS, dstS);

  k_prep_frags<<<tilesum, 64, 0, stream>>>(pa, frags);
  k_embed_h<<<N_NODES, 128, 0, stream>>>(x, node_w, node_b, h);
  // layer-0 aggregation: gather, e0 recomputed in exact f32
  k_agg<true><<<N_NODES / 2, 256, 0, stream>>>(rowptr, perm, srcS,
                                               eattr, edge_w, edge_b,
                                               nullptr, h, agg);

  const int nodeGrid = (N_NODES + 63) / 64;  // 782
  for (int i = 0; i < 2; ++i) {
    hipMemsetAsync(bn_sum, 0, 512, stream);
    hipMemsetAsync(bn_sq, 0, 512, stream);
    k_node_conv<<<nodeGrid, 256, 0, stream>>>(h, agg, frags + offConvW1[i], frags + offConvW2[i],
                                              conv_b1 + i * 100, conv_b2 + i * 100,
                                              z, bn_sum, bn_sq);
    k_bn_final<<<1, 128, 0, stream>>>(bn_sum, bn_sq, bn_mu, bn_rs);
    // fused h-update + PQ' GEMM
    k_h_pq<<<nodeGrid, 256, 0, stream>>>(h, z, bn_mu, bn_rs,
                                         bn_gamma + i * 100, bn_beta + i * 100,
                                         frags + offPQ[i], PQt);
    if (i == 0) {
      k_edge0<<<N_EDGES / 64, 256, 0, stream>>>(
          eattr, PQt, srcS, dstS, perm, edge_w, edge_b,
          frags + offW1c[0], frags + offW2e[0],
          emlp_b1, emlp_b2, e);
      // layer-1 aggregation: e is pos-ordered -> sequential reads
      k_agg<false><<<N_NODES / 2, 256, 0, stream>>>(rowptr, perm, srcS,
                                                    nullptr, nullptr, nullptr,
                                                    e, h, agg);
    } else {
      k_node_rs<<<nodeGrid, 256, 0, stream>>>(h, frags + offRS, RSt);
      k_edge1<<<N_EDGES / 64, 256, 0, stream>>>(
          e, PQt, RSt, srcS, dstS, perm,
          frags + offW1c[1], frags + offW2e[1],
          emlp_b1 + 100, emlp_b2 + 100,
          frags + offC, frags + offM2, frags + offM3,
          mlp_b1, mlp_b2, mlp_b3, (float*)d_out);
    }
  }
}

// Round 11
// 1508.638 us; speedup vs baseline: 1.4529x; 1.4529x over previous
//
#include <hip/hip_runtime.h>
#include <hip/hip_bf16.h>

#define N_NODES 50000
#define N_EDGES 800000
#define HDIM 100
#define ESTR 104   // e row stride (f16): 208B, 16B-aligned; cols 100..103 exact zero

typedef _Float16 half8_t __attribute__((ext_vector_type(8)));
typedef _Float16 half4_t __attribute__((ext_vector_type(4)));
typedef float f32x4_t __attribute__((ext_vector_type(4)));

// ---------------- weight fragment prep ----------------
// frag element ((t*ksteps + s)*64 + lane)*8 + i == B[s*32+(lane>>4)*8+i][t*16+(lane&15)]
struct FragDesc {
  const float* src; int stride; int K; int N; int outOff; int ksteps; int ntiles;
};
struct PrepArgs {
  FragDesc d[20];
  int prefix[21];
  int ndesc;
};

__global__ void k_prep_frags(PrepArgs args, _Float16* __restrict__ out) {
  int b = blockIdx.x;
  int di = 0;
  while (di + 1 < args.ndesc && b >= args.prefix[di + 1]) di++;
  FragDesc d = args.d[di];
  int local = b - args.prefix[di];
  int t = local / d.ksteps;
  int s = local % d.ksteps;
  int lane = threadIdx.x;            // 64 threads
  int col = t * 16 + (lane & 15);
  int kb = s * 32 + (lane >> 4) * 8;
  _Float16* o = out + d.outOff + (size_t)((t * d.ksteps + s) * 64 + lane) * 8;
  #pragma unroll
  for (int i = 0; i < 8; ++i) {
    int k = kb + i;
    float v = (k < d.K && col < d.N) ? d.src[(size_t)k * d.stride + col] : 0.0f;
    o[i] = (_Float16)v;
  }
}

// diagnostic: if workspace too small, encode ws_size (MB) into the output
__global__ void k_ws_probe(float* out, float mb) { out[0] = mb; }

// ---------------- CSR build (dst-sorted edge permutation) ----------------
__global__ void k_hist(const int* __restrict__ dst, int* __restrict__ cnt) {
  for (int e = blockIdx.x * blockDim.x + threadIdx.x; e < N_EDGES;
       e += gridDim.x * blockDim.x)
    atomicAdd(&cnt[dst[e]], 1);
}

// single-block exclusive scan: cnt -> rowptr[N+1], cursor[N].
// NOTE: cnt may alias cursor (cv read before overwrite; each n owned by one thread).
__global__ __launch_bounds__(1024) void k_scan(const int* cnt,
                                               int* rowptr,
                                               int* cursor) {
  __shared__ int part[1024];
  int t = threadIdx.x;
  const int CH = (N_NODES + 1023) / 1024;   // 49
  int base = t * CH;
  int s = 0;
  for (int i = 0; i < CH; ++i) {
    int n = base + i;
    if (n < N_NODES) s += cnt[n];
  }
  part[t] = s;
  __syncthreads();
  for (int off = 1; off < 1024; off <<= 1) {
    int v = 0;
    if (t >= off) v = part[t - off];
    __syncthreads();
    if (t >= off) part[t] += v;
    __syncthreads();
  }
  int run = (t == 0) ? 0 : part[t - 1];
  for (int i = 0; i < CH; ++i) {
    int n = base + i;
    if (n <= N_NODES) {
      rowptr[n] = run;
      if (n < N_NODES) {
        int cv = cnt[n];          // read BEFORE cursor write (alias-safe)
        cursor[n] = run;
        run += cv;
      }
    }
  }
}

__global__ void k_perm(const int* __restrict__ src, const int* __restrict__ dst,
                       int* __restrict__ cursor, int* __restrict__ perm,
                       int* __restrict__ srcS, int* __restrict__ dstS) {
  for (int e = blockIdx.x * blockDim.x + threadIdx.x; e < N_EDGES;
       e += gridDim.x * blockDim.x) {
    int d = dst[e];
    int pos = atomicAdd(&cursor[d], 1);
    perm[pos] = e;
    srcS[pos] = src[e];
    dstS[pos] = d;
  }
}

// ---------------- gather aggregation (no atomics) ----------------
// agg[n][j] = sum over in-edges of relu(h[src] + e_edge[j]).
// L0: e0 recomputed exactly in f32 from attr (8-dot, LDS-staged edge_w); attr via perm.
// !L0: e stored in pos order -> fully sequential reads.
template<bool L0>
__global__ __launch_bounds__(256) void k_agg(
    const int* __restrict__ rowptr, const int* __restrict__ perm,
    const int* __restrict__ srcS,
    const float* __restrict__ attr, const float* __restrict__ ew,
    const float* __restrict__ ebias,
    const _Float16* __restrict__ e,
    const float* __restrict__ h, float* __restrict__ agg) {
  __shared__ float EwL[800];
  __shared__ float ebL[128];
  int tid = threadIdx.x;
  if constexpr (L0) {
    for (int idx = tid; idx < 800; idx += 256) EwL[idx] = ew[idx];
    if (tid < 128) ebL[tid] = (tid < HDIM) ? ebias[tid] : 0.0f;
    __syncthreads();
  }
  int n = blockIdx.x * 2 + (tid >> 7);
  int j = tid & 127;
  if (n >= N_NODES || j >= HDIM) return;
  float acc = 0.0f;
  int p0 = rowptr[n], p1 = rowptr[n + 1];
  for (int pos = p0; pos < p1; ++pos) {
    int s = srcS[pos];
    float m;
    if constexpr (L0) {
      int eid = perm[pos];
      const float* ap = attr + (size_t)eid * 8;
      float e0 = ebL[j];
      #pragma unroll
      for (int k = 0; k < 8; ++k) e0 += ap[k] * EwL[k * HDIM + j];
      m = h[(size_t)s * HDIM + j] + e0;
    } else {
      m = h[(size_t)s * HDIM + j] + (float)e[(size_t)pos * ESTR + j];
    }
    acc += fmaxf(m, 0.0f);
  }
  agg[(size_t)n * HDIM + j] = acc;
}

// ---------------- small helpers ----------------
__device__ __forceinline__ half8_t h8_zero() {
  half8_t a;
  #pragma unroll
  for (int i = 0; i < 8; ++i) a[i] = (_Float16)0.0f;
  return a;
}

// XOR swizzle on 16B chunks inside a [16][128] f16 row-major tile (G4).
__device__ __forceinline__ int swz_idx(int r, int c) {
  int chunk = (c >> 3) ^ (r & 7);
  return r * 128 + chunk * 8 + (c & 7);
}

// A-fragment load from an f32 [rows][100] buffer. MODE 1: relu(v), 2: h+agg
template<int MODE>
__device__ __forceinline__ void load_a_node(const float* hp0,
                                            const float* ap0,
                                            int row, int lane, half8_t av[4]) {
  int g = lane >> 4;
  bool rv = (row < N_NODES);
  const float* hp = hp0 + (size_t)row * HDIM;
  const float* ap = ap0 + (size_t)row * HDIM;
  #pragma unroll
  for (int s = 0; s < 4; ++s) {
    int kb = s * 32 + g * 8;
    half8_t a = h8_zero();
    if (rv && kb < HDIM) {
      float f[8];
      #pragma unroll
      for (int i = 0; i < 8; ++i) f[i] = 0.0f;
      if (kb + 8 <= HDIM) {
        float4 v0 = *(const float4*)(hp + kb);
        float4 v1 = *(const float4*)(hp + kb + 4);
        f[0] = v0.x; f[1] = v0.y; f[2] = v0.z; f[3] = v0.w;
        f[4] = v1.x; f[5] = v1.y; f[6] = v1.z; f[7] = v1.w;
        if constexpr (MODE == 2) {
          float4 u0 = *(const float4*)(ap + kb);
          float4 u1 = *(const float4*)(ap + kb + 4);
          f[0] += u0.x; f[1] += u0.y; f[2] += u0.z; f[3] += u0.w;
          f[4] += u1.x; f[5] += u1.y; f[6] += u1.z; f[7] += u1.w;
        }
      } else {  // kb == 96: 4 valid elements
        float4 v0 = *(const float4*)(hp + kb);
        f[0] = v0.x; f[1] = v0.y; f[2] = v0.z; f[3] = v0.w;
        if constexpr (MODE == 2) {
          float4 u0 = *(const float4*)(ap + kb);
          f[0] += u0.x; f[1] += u0.y; f[2] += u0.z; f[3] += u0.w;
        }
      }
      #pragma unroll
      for (int i = 0; i < 8; ++i) {
        float v = f[i];
        if constexpr (MODE == 1) v = fmaxf(v, 0.0f);
        a[i] = (_Float16)v;
      }
    }
    av[s] = a;
  }
}

template<int NT, int KS>
__device__ __forceinline__ void mfma_tiles(const half8_t* av, const _Float16* __restrict__ fb,
                                           int lane, f32x4_t* acc) {
  #pragma unroll
  for (int t = 0; t < NT; ++t) {
    #pragma unroll
    for (int s = 0; s < KS; ++s) {
      half8_t bv = *(const half8_t*)(fb + (size_t)(((t * KS + s) * 64 + lane) << 3));
      acc[t] = __builtin_amdgcn_mfma_f32_16x16x32_f16(av[s], bv, acc[t], 0, 0, 0);
    }
  }
}

template<int KS>
__device__ __forceinline__ void lds_read_a(const _Float16* L, int lane, half8_t* av) {
  int r = lane & 15;
  int g = lane >> 4;
  #pragma unroll
  for (int s = 0; s < KS; ++s) {
    int kb = s * 32 + g * 8;
    av[s] = *(const half8_t*)&L[swz_idx(r, kb)];
  }
}

// ---------------- embeddings ----------------
__global__ void k_embed_h(const float* __restrict__ x, const float* __restrict__ w,
                          const float* __restrict__ bias, float* __restrict__ h) {
  int n = blockIdx.x;
  int j = threadIdx.x;
  if (j >= HDIM) return;
  float acc = bias[j];
  #pragma unroll
  for (int k = 0; k < 16; ++k) acc += x[n * 16 + k] * w[k * HDIM + j];
  h[(size_t)n * HDIM + j] = acc;
}

// ---------------- node-side kernels ----------------
// GINEConv MLP + BN partial stats. z aliases agg -> no __restrict__.
__global__ __launch_bounds__(256) void k_node_conv(
    const float* __restrict__ h, const float* agg,
    const _Float16* __restrict__ fb1, const _Float16* __restrict__ fb2,
    const float* __restrict__ b1, const float* __restrict__ b2,
    float* z, float* __restrict__ bn_sum, float* __restrict__ bn_sq) {
  __shared__ __align__(16) _Float16 lds[4][2048];
  int lane = threadIdx.x & 63;
  int wave = threadIdx.x >> 6;
  _Float16* L = lds[wave];
  int mbase = (blockIdx.x * 4 + wave) * 16;

  half8_t av[4];
  load_a_node<2>(h, agg, mbase + (lane & 15), lane, av);
  f32x4_t acc[7];
  #pragma unroll
  for (int t = 0; t < 7; ++t) acc[t] = (f32x4_t){0.f, 0.f, 0.f, 0.f};
  mfma_tiles<7, 4>(av, fb1, lane, acc);

  #pragma unroll
  for (int t = 0; t < 7; ++t) {
    int j = t * 16 + (lane & 15);
    float bias = (j < HDIM) ? b1[j] : 0.0f;
    #pragma unroll
    for (int q = 0; q < 4; ++q) {
      int r = (lane >> 4) * 4 + q;
      float v = fmaxf(acc[t][q] + bias, 0.0f);
      if (j >= HDIM) v = 0.0f;
      L[swz_idx(r, j)] = (_Float16)v;
    }
  }
  { int r = lane >> 2; int c0 = 112 + (lane & 3) * 4;
    #pragma unroll
    for (int i = 0; i < 4; ++i) L[swz_idx(r, c0 + i)] = (_Float16)0.0f;
  }
  __builtin_amdgcn_sched_barrier(0);

  half8_t av2[4];
  lds_read_a<4>(L, lane, av2);
  f32x4_t acc2[7];
  #pragma unroll
  for (int t = 0; t < 7; ++t) acc2[t] = (f32x4_t){0.f, 0.f, 0.f, 0.f};
  mfma_tiles<7, 4>(av2, fb2, lane, acc2);
  __builtin_amdgcn_sched_barrier(0);

  #pragma unroll
  for (int t = 0; t < 7; ++t) {
    int j = t * 16 + (lane & 15);
    float bias = (j < HDIM) ? b2[j] : 0.0f;
    float colsum = 0.0f, colsq = 0.0f;
    #pragma unroll
    for (int q = 0; q < 4; ++q) {
      int row = mbase + (lane >> 4) * 4 + q;
      float v = acc2[t][q] + bias;
      bool ok = (row < N_NODES) && (j < HDIM);
      if (ok) z[(size_t)row * HDIM + j] = v;
      float sv = ok ? v : 0.0f;
      colsum += sv; colsq += sv * sv;
    }
    colsum += __shfl_xor(colsum, 16);
    colsum += __shfl_xor(colsum, 32);
    colsq  += __shfl_xor(colsq, 16);
    colsq  += __shfl_xor(colsq, 32);
    if (lane < 16 && j < HDIM) {
      atomicAdd(&bn_sum[j], colsum);
      atomicAdd(&bn_sq[j], colsq);
    }
  }
}

__global__ void k_bn_final(const float* __restrict__ bn_sum, const float* __restrict__ bn_sq,
                           float* __restrict__ bn_mu, float* __restrict__ bn_rs) {
  int j = threadIdx.x;
  if (j >= HDIM) return;
  float mu = bn_sum[j] / (float)N_NODES;
  float var = bn_sq[j] / (float)N_NODES - mu * mu;
  bn_mu[j] = mu;
  bn_rs[j] = rsqrtf(var + 1e-5f);
}

// fused h-update + PQt GEMM
__global__ __launch_bounds__(256) void k_h_pq(
    float* h, const float* z,
    const float* __restrict__ bn_mu, const float* __restrict__ bn_rs,
    const float* __restrict__ gamma, const float* __restrict__ beta,
    const _Float16* __restrict__ fb, _Float16* __restrict__ PQt) {
  int lane = threadIdx.x & 63;
  int wave = threadIdx.x >> 6;
  int c = lane & 15, g = lane >> 4;
  int mbase = (blockIdx.x * 4 + wave) * 16;
  int row = mbase + c;
  bool rv = row < N_NODES;
  float* hp = h + (size_t)row * HDIM;
  const float* zp = z + (size_t)row * HDIM;

  half8_t av[4];
  #pragma unroll
  for (int s = 0; s < 4; ++s) {
    int kb = s * 32 + g * 8;
    half8_t a = h8_zero();
    if (rv && kb < HDIM) {
      int lim = (kb + 8 <= HDIM) ? 8 : 4;
      float zf[8], hf[8], mu[8], rs[8], ga[8], be[8];
      { float4 v = *(const float4*)(zp + kb);
        zf[0]=v.x; zf[1]=v.y; zf[2]=v.z; zf[3]=v.w; }
      { float4 v = *(const float4*)(hp + kb);
        hf[0]=v.x; hf[1]=v.y; hf[2]=v.z; hf[3]=v.w; }
      { float4 v = *(const float4*)(bn_mu + kb);
        mu[0]=v.x; mu[1]=v.y; mu[2]=v.z; mu[3]=v.w; }
      { float4 v = *(const float4*)(bn_rs + kb);
        rs[0]=v.x; rs[1]=v.y; rs[2]=v.z; rs[3]=v.w; }
      { float4 v = *(const float4*)(gamma + kb);
        ga[0]=v.x; ga[1]=v.y; ga[2]=v.z; ga[3]=v.w; }
      { float4 v = *(const float4*)(beta + kb);
        be[0]=v.x; be[1]=v.y; be[2]=v.z; be[3]=v.w; }
      if (lim == 8) {
        { float4 v = *(const float4*)(zp + kb + 4);
          zf[4]=v.x; zf[5]=v.y; zf[6]=v.z; zf[7]=v.w; }
        { float4 v = *(const float4*)(hp + kb + 4);
          hf[4]=v.x; hf[5]=v.y; hf[6]=v.z; hf[7]=v.w; }
        { float4 v = *(const float4*)(bn_mu + kb + 4);
          mu[4]=v.x; mu[5]=v.y; mu[6]=v.z; mu[7]=v.w; }
        { float4 v = *(const float4*)(bn_rs + kb + 4);
          rs[4]=v.x; rs[5]=v.y; rs[6]=v.z; rs[7]=v.w; }
        { float4 v = *(const float4*)(gamma + kb + 4);
          ga[4]=v.x; ga[5]=v.y; ga[6]=v.z; ga[7]=v.w; }
        { float4 v = *(const float4*)(beta + kb + 4);
          be[4]=v.x; be[5]=v.y; be[6]=v.z; be[7]=v.w; }
      }
      float hn[8];
      #pragma unroll
      for (int i = 0; i < 8; ++i) hn[i] = 0.0f;
      for (int i = 0; i < 8; ++i) {
        if (i < lim) {
          float zn = (zf[i] - mu[i]) * rs[i] * ga[i] + be[i];
          hn[i] = 0.5f * (hf[i] + fmaxf(zn, 0.0f));
          a[i] = (_Float16)hn[i];
        }
      }
      { float4 v; v.x=hn[0]; v.y=hn[1]; v.z=hn[2]; v.w=hn[3];
        *(float4*)(hp + kb) = v; }
      if (lim == 8) {
        float4 v; v.x=hn[4]; v.y=hn[5]; v.z=hn[6]; v.w=hn[7];
        *(float4*)(hp + kb + 4) = v;
      }
    }
    av[s] = a;
  }

  f32x4_t acc[14];
  #pragma unroll
  for (int t = 0; t < 14; ++t) acc[t] = (f32x4_t){0.f, 0.f, 0.f, 0.f};
  mfma_tiles<14, 4>(av, fb, lane, acc);
  #pragma unroll
  for (int q = 0; q < 4; ++q) {
    int orow = mbase + (lane >> 4) * 4 + q;
    if (orow >= N_NODES) continue;
    half8_t hp8, hq8;
    #pragma unroll
    for (int t = 0; t < 8; ++t) {
      hp8[t] = (t < 7) ? (_Float16)acc[t][q] : (_Float16)0.0f;
      hq8[t] = (t < 7) ? (_Float16)acc[7 + t][q] : (_Float16)0.0f;
    }
    *(half8_t*)(PQt + (size_t)orow * 256 + c * 8) = hp8;
    *(half8_t*)(PQt + (size_t)orow * 256 + 128 + c * 8) = hq8;
  }
}

// RS' GEMM (reads h, relu'd): RS' [node][128]: R slot c*4+t, S slot 64+c*4+t
__global__ __launch_bounds__(256) void k_node_rs(const float* __restrict__ h,
                                                 const _Float16* __restrict__ fb,
                                                 _Float16* __restrict__ out) {
  int lane = threadIdx.x & 63;
  int wave = threadIdx.x >> 6;
  int c = lane & 15;
  int mbase = (blockIdx.x * 4 + wave) * 16;
  half8_t av[4];
  load_a_node<1>(h, h, mbase + c, lane, av);
  f32x4_t acc[8];
  #pragma unroll
  for (int t = 0; t < 8; ++t) acc[t] = (f32x4_t){0.f, 0.f, 0.f, 0.f};
  mfma_tiles<8, 4>(av, fb, lane, acc);
  #pragma unroll
  for (int q = 0; q < 4; ++q) {
    int row = mbase + (lane >> 4) * 4 + q;
    if (row >= N_NODES) continue;
    half4_t hr, hs;
    #pragma unroll
    for (int t = 0; t < 4; ++t) {
      hr[t] = (_Float16)acc[t][q];
      hs[t] = (_Float16)acc[4 + t][q];
    }
    *(half4_t*)(out + (size_t)row * 128 + c * 4) = hr;
    *(half4_t*)(out + (size_t)row * 128 + 64 + c * 4) = hs;
  }
}

// ---------------- layer-0 edge kernel (pos-ordered; e0 never in HBM) ----------------
__global__ __launch_bounds__(256) void k_edge0(
    const float* __restrict__ attr,
    const _Float16* __restrict__ PQ,
    const int* __restrict__ srcS, const int* __restrict__ dstS,
    const int* __restrict__ perm,
    const float* __restrict__ ew, const float* __restrict__ ebias,
    const _Float16* __restrict__ fbW1c, const _Float16* __restrict__ fbW2,
    const float* __restrict__ b1, const float* __restrict__ b2,
    _Float16* __restrict__ e) {
  __shared__ __align__(16) _Float16 lds[4][2048];
  __shared__ float EwL[800];
  __shared__ float ebL[112];
  int tid = threadIdx.x;
  for (int idx = tid; idx < 800; idx += 256) EwL[idx] = ew[idx];
  if (tid < 112) ebL[tid] = (tid < HDIM) ? ebias[tid] : 0.0f;
  __syncthreads();

  int lane = tid & 63;
  int wave = tid >> 6;
  _Float16* L = lds[wave];
  int mbase = (blockIdx.x * 4 + wave) * 16;
  int c = lane & 15, g = lane >> 4;

  int sn[4], dn[4], pv[4];
  #pragma unroll
  for (int q = 0; q < 4; ++q) {
    int row = mbase + g * 4 + q;
    sn[q] = srcS[row]; dn[q] = dstS[row]; pv[q] = perm[row];
  }

  half8_t Pf[4], Qf[4];
  #pragma unroll
  for (int q = 0; q < 4; ++q) {
    Pf[q] = *(const half8_t*)(PQ + (size_t)sn[q] * 256 + c * 8);
    Qf[q] = *(const half8_t*)(PQ + (size_t)dn[q] * 256 + 128 + c * 8);
  }

  // attr rows (gathered via perm)
  float af[4][8];
  #pragma unroll
  for (int q = 0; q < 4; ++q) {
    const float* ap = attr + (size_t)pv[q] * 8;
    float4 a0 = *(const float4*)ap;
    float4 a1 = *(const float4*)(ap + 4);
    af[q][0] = a0.x; af[q][1] = a0.y; af[q][2] = a0.z; af[q][3] = a0.w;
    af[q][4] = a1.x; af[q][5] = a1.y; af[q][6] = a1.z; af[q][7] = a1.w;
  }

  // e0 in f32 (same FMA order as original embed_e) -> regs + f16 into LDS tile
  float e0r[7][4];
  #pragma unroll
  for (int t = 0; t < 7; ++t) {
    int j = t * 16 + c;
    #pragma unroll
    for (int q = 0; q < 4; ++q) {
      float v = 0.0f;
      if (j < HDIM) {
        v = ebL[j];
        #pragma unroll
        for (int k = 0; k < 8; ++k) v += af[q][k] * EwL[k * HDIM + j];
      }
      e0r[t][q] = v;
      L[swz_idx(g * 4 + q, j)] = (_Float16)v;
    }
  }
  { int r = lane >> 2; int c0 = 112 + (lane & 3) * 4;
    #pragma unroll
    for (int i = 0; i < 4; ++i) L[swz_idx(r, c0 + i)] = (_Float16)0.0f;
  }
  __builtin_amdgcn_sched_barrier(0);

  half8_t av[4];
  lds_read_a<4>(L, lane, av);
  __builtin_amdgcn_sched_barrier(0);
  f32x4_t acc[7];
  #pragma unroll
  for (int t = 0; t < 7; ++t) acc[t] = (f32x4_t){0.f, 0.f, 0.f, 0.f};
  mfma_tiles<7, 4>(av, fbW1c, lane, acc);

  #pragma unroll
  for (int t = 0; t < 7; ++t) {
    int j = t * 16 + c;
    float bias = (j < HDIM) ? b1[j] : 0.0f;
    #pragma unroll
    for (int q = 0; q < 4; ++q) {
      int r = g * 4 + q;
      float v = 0.0f;
      if (j < HDIM)
        v = fmaxf(acc[t][q] + bias + (float)Pf[q][t] + (float)Qf[q][t], 0.0f);
      L[swz_idx(r, j)] = (_Float16)v;
    }
  }
  __builtin_amdgcn_sched_barrier(0);

  half8_t av2[4];
  lds_read_a<4>(L, lane, av2);
  f32x4_t acc2[7];
  #pragma unroll
  for (int t = 0; t < 7; ++t) acc2[t] = (f32x4_t){0.f, 0.f, 0.f, 0.f};
  mfma_tiles<7, 4>(av2, fbW2, lane, acc2);
  __builtin_amdgcn_sched_barrier(0);

  #pragma unroll
  for (int t = 0; t < 7; ++t) {
    int j = t * 16 + c;
    float b2v = (j < HDIM) ? b2[j] : 0.0f;
    #pragma unroll
    for (int q = 0; q < 4; ++q) {
      int row = mbase + g * 4 + q;
      float eold = (float)(_Float16)e0r[t][q];
      float enew = eold + 0.5f * (acc2[t][q] + b2v);
      if (j < ESTR)
        e[(size_t)row * ESTR + j] = (j < HDIM) ? (_Float16)enew : (_Float16)0.0f;
    }
  }
}

// ---------------- layer-1 edge kernel + fused classifier (pos-ordered) ----------------
__global__ __launch_bounds__(256) void k_edge1(
    const _Float16* __restrict__ e,
    const _Float16* __restrict__ PQ, const _Float16* __restrict__ RS,
    const int* __restrict__ srcS, const int* __restrict__ dstS,
    const int* __restrict__ perm,
    const _Float16* __restrict__ fbW1c, const _Float16* __restrict__ fbW2,
    const float* __restrict__ b1, const float* __restrict__ b2,
    const _Float16* __restrict__ fbC, const _Float16* __restrict__ fbM2,
    const _Float16* __restrict__ fbM3,
    const float* __restrict__ mb1, const float* __restrict__ mb2,
    const float* __restrict__ mb3, float* __restrict__ out) {
  __shared__ __align__(16) _Float16 lds[4][2048];
  int lane = threadIdx.x & 63;
  int wave = threadIdx.x >> 6;
  _Float16* L = lds[wave];
  int mbase = (blockIdx.x * 4 + wave) * 16;
  int c = lane & 15, g = lane >> 4;

  // e A-loads issued FIRST (independent of indices) so stage-1 MFMA
  // only waits on these, not the whole VMEM queue.
  half8_t av[4];
  {
    const _Float16* ep = e + (size_t)(mbase + c) * ESTR;
    #pragma unroll
    for (int s = 0; s < 3; ++s)
      av[s] = *(const half8_t*)(ep + s * 32 + g * 8);
    av[3] = (g == 0) ? *(const half8_t*)(ep + 96) : h8_zero();
  }

  int sn[4], dn[4];
  #pragma unroll
  for (int q = 0; q < 4; ++q) {
    int row = mbase + g * 4 + q;
    sn[q] = srcS[row]; dn[q] = dstS[row];
  }
  half8_t Pf[4], Qf[4];
  #pragma unroll
  for (int q = 0; q < 4; ++q) {
    Pf[q] = *(const half8_t*)(PQ + (size_t)sn[q] * 256 + c * 8);
    Qf[q] = *(const half8_t*)(PQ + (size_t)dn[q] * 256 + 128 + c * 8);
  }

  f32x4_t acc[7];
  #pragma unroll
  for (int t = 0; t < 7; ++t) acc[t] = (f32x4_t){0.f, 0.f, 0.f, 0.f};
  mfma_tiles<7, 4>(av, fbW1c, lane, acc);

  #pragma unroll
  for (int t = 0; t < 7; ++t) {
    int j = t * 16 + c;
    float bias = (j < HDIM) ? b1[j] : 0.0f;
    #pragma unroll
    for (int q = 0; q < 4; ++q) {
      int r = g * 4 + q;
      float v = 0.0f;
      if (j < HDIM)
        v = fmaxf(acc[t][q] + bias + (float)Pf[q][t] + (float)Qf[q][t], 0.0f);
      L[swz_idx(r, j)] = (_Float16)v;
    }
  }
  { int r = lane >> 2; int c0 = 112 + (lane & 3) * 4;
    #pragma unroll
    for (int i = 0; i < 4; ++i) L[swz_idx(r, c0 + i)] = (_Float16)0.0f;
  }
  __builtin_amdgcn_sched_barrier(0);

  // R/S gathers (hidden under stage-2 MFMA)
  half4_t Rf[4], Sf[4];
  #pragma unroll
  for (int q = 0; q < 4; ++q) {
    Rf[q] = *(const half4_t*)(RS + (size_t)sn[q] * 128 + c * 4);
    Sf[q] = *(const half4_t*)(RS + (size_t)dn[q] * 128 + 64 + c * 4);
  }

  half8_t av2[4];
  lds_read_a<4>(L, lane, av2);
  f32x4_t acc2[7];
  #pragma unroll
  for (int t = 0; t < 7; ++t) acc2[t] = (f32x4_t){0.f, 0.f, 0.f, 0.f};
  mfma_tiles<7, 4>(av2, fbW2, lane, acc2);
  __builtin_amdgcn_sched_barrier(0);

  // epilogue 2: e2 -> LDS; eold via global re-read (L2-hot from stage 1)
  #pragma unroll
  for (int t = 0; t < 7; ++t) {
    int j = t * 16 + c;
    float bias = (j < HDIM) ? b2[j] : 0.0f;
    #pragma unroll
    for (int q = 0; q < 4; ++q) {
      int row = mbase + g * 4 + q;
      float v = 0.0f;
      if (j < HDIM) {
        float eold = (float)e[(size_t)row * ESTR + j];
        v = eold + 0.5f * (acc2[t][q] + bias);
      }
      int r = g * 4 + q;
      L[swz_idx(r, j)] = (_Float16)v;
    }
  }
  __builtin_amdgcn_sched_barrier(0);

  // classifier stage 1: t1 = relu(e2@C + R + S + mb1), 50 outs
  half8_t av3[4];
  lds_read_a<4>(L, lane, av3);
  f32x4_t acc3[4];
  #pragma unroll
  for (int t = 0; t < 4; ++t) acc3[t] = (f32x4_t){0.f, 0.f, 0.f, 0.f};
  mfma_tiles<4, 4>(av3, fbC, lane, acc3);
  __builtin_amdgcn_sched_barrier(0);
  #pragma unroll
  for (int t = 0; t < 4; ++t) {
    int j = t * 16 + c;
    float bias = (j < 50) ? mb1[j] : 0.0f;
    #pragma unroll
    for (int q = 0; q < 4; ++q) {
      float v = 0.0f;
      if (j < 50)
        v = fmaxf(acc3[t][q] + bias + (float)Rf[q][t] + (float)Sf[q][t], 0.0f);
      int r = g * 4 + q;
      L[swz_idx(r, j)] = (_Float16)v;
    }
  }
  __builtin_amdgcn_sched_barrier(0);
  // classifier stage 2: t2 = relu(t1@M2 + mb2), 25 outs
  half8_t av4[2];
  lds_read_a<2>(L, lane, av4);
  f32x4_t acc4[2];
  #pragma unroll
  for (int t = 0; t < 2; ++t) acc4[t] = (f32x4_t){0.f, 0.f, 0.f, 0.f};
  mfma_tiles<2, 2>(av4, fbM2, lane, acc4);
  __builtin_amdgcn_sched_barrier(0);
  #pragma unroll
  for (int t = 0; t < 2; ++t) {
    int j = t * 16 + c;
    float bias = (j < 25) ? mb2[j] : 0.0f;
    #pragma unroll
    for (int q = 0; q < 4; ++q) {
      float v = (j < 25) ? fmaxf(acc4[t][q] + bias, 0.0f) : 0.0f;
      int r = g * 4 + q;
      L[swz_idx(r, j)] = (_Float16)v;
    }
  }
  __builtin_amdgcn_sched_barrier(0);
  // classifier stage 3: out = t2@M3 + mb3 (scattered to original edge ids)
  half8_t av5[1];
  lds_read_a<1>(L, lane, av5);
  f32x4_t acc5 = (f32x4_t){0.f, 0.f, 0.f, 0.f};
  {
    half8_t bv = *(const half8_t*)(fbM3 + (size_t)(lane << 3));
    acc5 = __builtin_amdgcn_mfma_f32_16x16x32_f16(av5[0], bv, acc5, 0, 0, 0);
  }
  if (c < 2) {
    float bias = mb3[c];
    #pragma unroll
    for (int q = 0; q < 4; ++q) {
      int row = mbase + g * 4 + q;
      out[(size_t)perm[row] * 2 + c] = acc5[q] + bias;
    }
  }
}

// ---------------- host launch ----------------
extern "C" void kernel_launch(void* const* d_in, const int* in_sizes, int n_in,
                              void* d_out, int out_size, void* d_ws, size_t ws_size,
                              hipStream_t stream) {
  const float* x        = (const float*)d_in[0];
  const int*   ei       = (const int*)  d_in[1];
  const float* eattr    = (const float*)d_in[2];
  const float* node_w   = (const float*)d_in[3];
  const float* node_b   = (const float*)d_in[4];
  const float* edge_w   = (const float*)d_in[5];
  const float* edge_b   = (const float*)d_in[6];
  const float* conv_w1  = (const float*)d_in[7];
  const float* conv_b1  = (const float*)d_in[8];
  const float* conv_w2  = (const float*)d_in[9];
  const float* conv_b2  = (const float*)d_in[10];
  const float* bn_gamma = (const float*)d_in[11];
  const float* bn_beta  = (const float*)d_in[12];
  const float* emlp_w1  = (const float*)d_in[13];
  const float* emlp_b1  = (const float*)d_in[14];
  const float* emlp_w2  = (const float*)d_in[15];
  const float* emlp_b2  = (const float*)d_in[16];
  const float* mlp_w1   = (const float*)d_in[17];
  const float* mlp_b1   = (const float*)d_in[18];
  const float* mlp_w2   = (const float*)d_in[19];
  const float* mlp_b2   = (const float*)d_in[20];
  const float* mlp_w3   = (const float*)d_in[21];
  const float* mlp_b3   = (const float*)d_in[22];
  const int* src = ei;
  const int* dst = ei + N_EDGES;

  char* ws = (char*)d_ws;
  size_t off = 0;
  auto alloc = [&](size_t bytes) -> void* {
    void* p = ws + off;
    off += (bytes + 255) & ~(size_t)255;
    return p;
  };
  _Float16* e    = (_Float16*)alloc((size_t)N_EDGES * ESTR * 2);   // 166.4 MB (pos order)
  float* h       = (float*)alloc((size_t)N_NODES * HDIM * 4);      //  20 MB
  float* agg     = (float*)alloc((size_t)N_NODES * HDIM * 4);      //  20 MB (z, RSt alias)
  _Float16* PQt  = (_Float16*)alloc((size_t)N_NODES * 256 * 2);    //  25.6 MB
  int* cursor    = (int*)alloc((size_t)N_NODES * 4);               //  0.2 MB (doubles as hist)
  int* rowptr    = (int*)alloc((size_t)(N_NODES + 1) * 4);         //  0.2 MB
  int* perm      = (int*)alloc((size_t)N_EDGES * 4);               //  3.2 MB
  int* srcS      = (int*)alloc((size_t)N_EDGES * 4);               //  3.2 MB
  int* dstS      = (int*)alloc((size_t)N_EDGES * 4);               //  3.2 MB
  float* bn_sum  = (float*)alloc(512);
  float* bn_sq   = (float*)alloc(512);
  float* bn_mu   = (float*)alloc(512);
  float* bn_rs   = (float*)alloc(512);
  _Float16* frags = (_Float16*)alloc(200000 * 2);                  //  0.4 MB
  float* z = agg;                 // alias: conv reads agg rows before writing same z rows
  _Float16* RSt = (_Float16*)agg; // alias: written at i==1 after z is dead

  if (off > ws_size) {
    k_ws_probe<<<1, 1, 0, stream>>>((float*)d_out, (float)(ws_size >> 20));
    return;
  }

  // fragment descriptor table
  PrepArgs pa;
  int nd = 0, tilesum = 0, fo = 0;
  auto add = [&](const float* sp, int stride, int K, int Ncols, int ksteps, int ntiles) -> int {
    pa.d[nd] = FragDesc{sp, stride, K, Ncols, fo, ksteps, ntiles};
    pa.prefix[nd] = tilesum;
    tilesum += ksteps * ntiles;
    ++nd;
    int ret = fo;
    fo += ksteps * ntiles * 512;
    return ret;
  };
  int offConvW1[2], offConvW2[2], offPQ[2], offW1c[2], offW2e[2];
  for (int i = 0; i < 2; ++i) {
    offConvW1[i] = add(conv_w1 + i * 10000, 100, 100, 100, 4, 7);
    offConvW2[i] = add(conv_w2 + i * 10000, 100, 100, 100, 4, 7);
    offPQ[i]     = add(emlp_w1 + i * 30000,         100, 100, 100, 4, 7);  // W1a (P)
                   add(emlp_w1 + i * 30000 + 10000, 100, 100, 100, 4, 7);  // W1b (Q), contiguous
    offW1c[i]    = add(emlp_w1 + i * 30000 + 20000, 100, 100, 100, 4, 7);
    offW2e[i]    = add(emlp_w2 + i * 10000, 100, 100, 100, 4, 7);
  }
  int offRS = add(mlp_w1,         50, 100, 50, 4, 4);   // R
              add(mlp_w1 + 5000,  50, 100, 50, 4, 4);   // S, contiguous
  int offC  = add(mlp_w1 + 10000, 50, 100, 50, 4, 4);
  int offM2 = add(mlp_w2, 25, 50, 25, 2, 2);
  int offM3 = add(mlp_w3, 2, 25, 2, 1, 1);
  pa.prefix[nd] = tilesum;
  pa.ndesc = nd;

  // CSR build (dst layer-invariant: one sort serves both layers)
  hipMemsetAsync(cursor, 0, (size_t)N_NODES * 4, stream);
  k_hist<<<2048, 256, 0, stream>>>(dst, cursor);
  k_scan<<<1, 1024, 0, stream>>>(cursor, rowptr, cursor);
  k_perm<<<2048, 256, 0, stream>>>(src, dst, cursor, perm, srcS, dstS);

  k_prep_frags<<<tilesum, 64, 0, stream>>>(pa, frags);
  k_embed_h<<<N_NODES, 128, 0, stream>>>(x, node_w, node_b, h);
  // layer-0 aggregation: gather, e0 recomputed in exact f32
  k_agg<true><<<N_NODES / 2, 256, 0, stream>>>(rowptr, perm, srcS,
                                               eattr, edge_w, edge_b,
                                               nullptr, h, agg);

  const int nodeGrid = (N_NODES + 63) / 64;  // 782
  for (int i = 0; i < 2; ++i) {
    hipMemsetAsync(bn_sum, 0, 512, stream);
    hipMemsetAsync(bn_sq, 0, 512, stream);
    k_node_conv<<<nodeGrid, 256, 0, stream>>>(h, agg, frags + offConvW1[i], frags + offConvW2[i],
                                              conv_b1 + i * 100, conv_b2 + i * 100,
                                              z, bn_sum, bn_sq);
    k_bn_final<<<1, 128, 0, stream>>>(bn_sum, bn_sq, bn_mu, bn_rs);
    // fused h-update + PQ' GEMM
    k_h_pq<<<nodeGrid, 256, 0, stream>>>(h, z, bn_mu, bn_rs,
                                         bn_gamma + i * 100, bn_beta + i * 100,
                                         frags + offPQ[i], PQt);
    if (i == 0) {
      k_edge0<<<N_EDGES / 64, 256, 0, stream>>>(
          eattr, PQt, srcS, dstS, perm, edge_w, edge_b,
          frags + offW1c[0], frags + offW2e[0],
          emlp_b1, emlp_b2, e);
      // layer-1 aggregation: e is pos-ordered -> sequential reads
      k_agg<false><<<N_NODES / 2, 256, 0, stream>>>(rowptr, perm, srcS,
                                                    nullptr, nullptr, nullptr,
                                                    e, h, agg);
    } else {
      k_node_rs<<<nodeGrid, 256, 0, stream>>>(h, frags + offRS, RSt);
      k_edge1<<<N_EDGES / 64, 256, 0, stream>>>(
          e, PQt, RSt, srcS, dstS, perm,
          frags + offW1c[1], frags + offW2e[1],
          emlp_b1 + 100, emlp_b2 + 100,
          frags + offC, frags + offM2, frags + offM3,
          mlp_b1, mlp_b2, mlp_b3, (float*)d_out);
    }
  }
}

// Round 12
// 1405.136 us; speedup vs baseline: 1.5599x; 1.0737x over previous
//
#include <hip/hip_runtime.h>
#include <hip/hip_bf16.h>

#define N_NODES 50000
#define N_EDGES 800000
#define HDIM 100
#define ESTR 104   // e row stride (f16): 208B, 16B-aligned; cols 100..103 exact zero

typedef _Float16 half8_t __attribute__((ext_vector_type(8)));
typedef _Float16 half4_t __attribute__((ext_vector_type(4)));
typedef float f32x4_t __attribute__((ext_vector_type(4)));

// ---------------- weight fragment prep ----------------
// frag element ((t*ksteps + s)*64 + lane)*8 + i == B[s*32+(lane>>4)*8+i][t*16+(lane&15)]
struct FragDesc {
  const float* src; int stride; int K; int N; int outOff; int ksteps; int ntiles;
};
struct PrepArgs {
  FragDesc d[20];
  int prefix[21];
  int ndesc;
};

__global__ void k_prep_frags(PrepArgs args, _Float16* __restrict__ out) {
  int b = blockIdx.x;
  int di = 0;
  while (di + 1 < args.ndesc && b >= args.prefix[di + 1]) di++;
  FragDesc d = args.d[di];
  int local = b - args.prefix[di];
  int t = local / d.ksteps;
  int s = local % d.ksteps;
  int lane = threadIdx.x;            // 64 threads
  int col = t * 16 + (lane & 15);
  int kb = s * 32 + (lane >> 4) * 8;
  _Float16* o = out + d.outOff + (size_t)((t * d.ksteps + s) * 64 + lane) * 8;
  #pragma unroll
  for (int i = 0; i < 8; ++i) {
    int k = kb + i;
    float v = (k < d.K && col < d.N) ? d.src[(size_t)k * d.stride + col] : 0.0f;
    o[i] = (_Float16)v;
  }
}

// diagnostic: if workspace too small, encode ws_size (MB) into the output
__global__ void k_ws_probe(float* out, float mb) { out[0] = mb; }

// ---------------- CSR build (dst-sorted edge permutation) ----------------
__global__ void k_hist(const int* __restrict__ dst, int* __restrict__ cnt) {
  for (int e = blockIdx.x * blockDim.x + threadIdx.x; e < N_EDGES;
       e += gridDim.x * blockDim.x)
    atomicAdd(&cnt[dst[e]], 1);
}

// single-block exclusive scan: cnt -> rowptr[N+1], cursor[N].
// NOTE: cnt may alias cursor (cv read before overwrite; each n owned by one thread).
__global__ __launch_bounds__(1024) void k_scan(const int* cnt,
                                               int* rowptr,
                                               int* cursor) {
  __shared__ int part[1024];
  int t = threadIdx.x;
  const int CH = (N_NODES + 1023) / 1024;   // 49
  int base = t * CH;
  int s = 0;
  for (int i = 0; i < CH; ++i) {
    int n = base + i;
    if (n < N_NODES) s += cnt[n];
  }
  part[t] = s;
  __syncthreads();
  for (int off = 1; off < 1024; off <<= 1) {
    int v = 0;
    if (t >= off) v = part[t - off];
    __syncthreads();
    if (t >= off) part[t] += v;
    __syncthreads();
  }
  int run = (t == 0) ? 0 : part[t - 1];
  for (int i = 0; i < CH; ++i) {
    int n = base + i;
    if (n <= N_NODES) {
      rowptr[n] = run;
      if (n < N_NODES) {
        int cv = cnt[n];          // read BEFORE cursor write (alias-safe)
        cursor[n] = run;
        run += cv;
      }
    }
  }
}

__global__ void k_perm(const int* __restrict__ src, const int* __restrict__ dst,
                       int* __restrict__ cursor, int* __restrict__ perm,
                       int* __restrict__ srcS, int* __restrict__ dstS) {
  for (int e = blockIdx.x * blockDim.x + threadIdx.x; e < N_EDGES;
       e += gridDim.x * blockDim.x) {
    int d = dst[e];
    int pos = atomicAdd(&cursor[d], 1);
    perm[pos] = e;
    srcS[pos] = src[e];
    dstS[pos] = d;
  }
}

// ---------------- gather aggregation (no atomics) ----------------
// agg[n][j] = sum over in-edges of relu(h[src] + e_edge[j]).
// L0: e0 recomputed exactly in f32 from attr (8-dot, LDS-staged edge_w); attr via perm.
// !L0: e stored in pos order -> fully sequential reads.
template<bool L0>
__global__ __launch_bounds__(256) void k_agg(
    const int* __restrict__ rowptr, const int* __restrict__ perm,
    const int* __restrict__ srcS,
    const float* __restrict__ attr, const float* __restrict__ ew,
    const float* __restrict__ ebias,
    const _Float16* __restrict__ e,
    const float* __restrict__ h, float* __restrict__ agg) {
  __shared__ float EwL[800];
  __shared__ float ebL[128];
  int tid = threadIdx.x;
  if constexpr (L0) {
    for (int idx = tid; idx < 800; idx += 256) EwL[idx] = ew[idx];
    if (tid < 128) ebL[tid] = (tid < HDIM) ? ebias[tid] : 0.0f;
    __syncthreads();
  }
  int n = blockIdx.x * 2 + (tid >> 7);
  int j = tid & 127;
  if (n >= N_NODES || j >= HDIM) return;
  float acc = 0.0f;
  int p0 = rowptr[n], p1 = rowptr[n + 1];
  for (int pos = p0; pos < p1; ++pos) {
    int s = srcS[pos];
    float m;
    if constexpr (L0) {
      int eid = perm[pos];
      const float* ap = attr + (size_t)eid * 8;
      float e0 = ebL[j];
      #pragma unroll
      for (int k = 0; k < 8; ++k) e0 += ap[k] * EwL[k * HDIM + j];
      m = h[(size_t)s * HDIM + j] + e0;
    } else {
      m = h[(size_t)s * HDIM + j] + (float)e[(size_t)pos * ESTR + j];
    }
    acc += fmaxf(m, 0.0f);
  }
  agg[(size_t)n * HDIM + j] = acc;
}

// ---------------- small helpers ----------------
__device__ __forceinline__ half8_t h8_zero() {
  half8_t a;
  #pragma unroll
  for (int i = 0; i < 8; ++i) a[i] = (_Float16)0.0f;
  return a;
}

// XOR swizzle on 16B chunks inside a [16][128] f16 row-major tile (G4).
__device__ __forceinline__ int swz_idx(int r, int c) {
  int chunk = (c >> 3) ^ (r & 7);
  return r * 128 + chunk * 8 + (c & 7);
}

// A-fragment load from an f32 [rows][100] buffer. MODE 1: relu(v), 2: h+agg
template<int MODE>
__device__ __forceinline__ void load_a_node(const float* hp0,
                                            const float* ap0,
                                            int row, int lane, half8_t av[4]) {
  int g = lane >> 4;
  bool rv = (row < N_NODES);
  const float* hp = hp0 + (size_t)row * HDIM;
  const float* ap = ap0 + (size_t)row * HDIM;
  #pragma unroll
  for (int s = 0; s < 4; ++s) {
    int kb = s * 32 + g * 8;
    half8_t a = h8_zero();
    if (rv && kb < HDIM) {
      float f[8];
      #pragma unroll
      for (int i = 0; i < 8; ++i) f[i] = 0.0f;
      if (kb + 8 <= HDIM) {
        float4 v0 = *(const float4*)(hp + kb);
        float4 v1 = *(const float4*)(hp + kb + 4);
        f[0] = v0.x; f[1] = v0.y; f[2] = v0.z; f[3] = v0.w;
        f[4] = v1.x; f[5] = v1.y; f[6] = v1.z; f[7] = v1.w;
        if constexpr (MODE == 2) {
          float4 u0 = *(const float4*)(ap + kb);
          float4 u1 = *(const float4*)(ap + kb + 4);
          f[0] += u0.x; f[1] += u0.y; f[2] += u0.z; f[3] += u0.w;
          f[4] += u1.x; f[5] += u1.y; f[6] += u1.z; f[7] += u1.w;
        }
      } else {  // kb == 96: 4 valid elements
        float4 v0 = *(const float4*)(hp + kb);
        f[0] = v0.x; f[1] = v0.y; f[2] = v0.z; f[3] = v0.w;
        if constexpr (MODE == 2) {
          float4 u0 = *(const float4*)(ap + kb);
          f[0] += u0.x; f[1] += u0.y; f[2] += u0.z; f[3] += u0.w;
        }
      }
      #pragma unroll
      for (int i = 0; i < 8; ++i) {
        float v = f[i];
        if constexpr (MODE == 1) v = fmaxf(v, 0.0f);
        a[i] = (_Float16)v;
      }
    }
    av[s] = a;
  }
}

template<int NT, int KS>
__device__ __forceinline__ void mfma_tiles(const half8_t* av, const _Float16* __restrict__ fb,
                                           int lane, f32x4_t* acc) {
  #pragma unroll
  for (int t = 0; t < NT; ++t) {
    #pragma unroll
    for (int s = 0; s < KS; ++s) {
      half8_t bv = *(const half8_t*)(fb + (size_t)(((t * KS + s) * 64 + lane) << 3));
      acc[t] = __builtin_amdgcn_mfma_f32_16x16x32_f16(av[s], bv, acc[t], 0, 0, 0);
    }
  }
}

template<int KS>
__device__ __forceinline__ void lds_read_a(const _Float16* L, int lane, half8_t* av) {
  int r = lane & 15;
  int g = lane >> 4;
  #pragma unroll
  for (int s = 0; s < KS; ++s) {
    int kb = s * 32 + g * 8;
    av[s] = *(const half8_t*)&L[swz_idx(r, kb)];
  }
}

// ---------------- embeddings ----------------
__global__ void k_embed_h(const float* __restrict__ x, const float* __restrict__ w,
                          const float* __restrict__ bias, float* __restrict__ h) {
  int n = blockIdx.x;
  int j = threadIdx.x;
  if (j >= HDIM) return;
  float acc = bias[j];
  #pragma unroll
  for (int k = 0; k < 16; ++k) acc += x[n * 16 + k] * w[k * HDIM + j];
  h[(size_t)n * HDIM + j] = acc;
}

// ---------------- node-side kernels ----------------
// GINEConv MLP + BN partial stats. z aliases agg -> no __restrict__.
__global__ __launch_bounds__(256) void k_node_conv(
    const float* __restrict__ h, const float* agg,
    const _Float16* __restrict__ fb1, const _Float16* __restrict__ fb2,
    const float* __restrict__ b1, const float* __restrict__ b2,
    float* z, float* __restrict__ bn_sum, float* __restrict__ bn_sq) {
  __shared__ __align__(16) _Float16 lds[4][2048];
  int lane = threadIdx.x & 63;
  int wave = threadIdx.x >> 6;
  _Float16* L = lds[wave];
  int mbase = (blockIdx.x * 4 + wave) * 16;

  half8_t av[4];
  load_a_node<2>(h, agg, mbase + (lane & 15), lane, av);
  f32x4_t acc[7];
  #pragma unroll
  for (int t = 0; t < 7; ++t) acc[t] = (f32x4_t){0.f, 0.f, 0.f, 0.f};
  mfma_tiles<7, 4>(av, fb1, lane, acc);

  #pragma unroll
  for (int t = 0; t < 7; ++t) {
    int j = t * 16 + (lane & 15);
    float bias = (j < HDIM) ? b1[j] : 0.0f;
    #pragma unroll
    for (int q = 0; q < 4; ++q) {
      int r = (lane >> 4) * 4 + q;
      float v = fmaxf(acc[t][q] + bias, 0.0f);
      if (j >= HDIM) v = 0.0f;
      L[swz_idx(r, j)] = (_Float16)v;
    }
  }
  { int r = lane >> 2; int c0 = 112 + (lane & 3) * 4;
    #pragma unroll
    for (int i = 0; i < 4; ++i) L[swz_idx(r, c0 + i)] = (_Float16)0.0f;
  }
  __builtin_amdgcn_sched_barrier(0);

  half8_t av2[4];
  lds_read_a<4>(L, lane, av2);
  f32x4_t acc2[7];
  #pragma unroll
  for (int t = 0; t < 7; ++t) acc2[t] = (f32x4_t){0.f, 0.f, 0.f, 0.f};
  mfma_tiles<7, 4>(av2, fb2, lane, acc2);
  __builtin_amdgcn_sched_barrier(0);

  #pragma unroll
  for (int t = 0; t < 7; ++t) {
    int j = t * 16 + (lane & 15);
    float bias = (j < HDIM) ? b2[j] : 0.0f;
    float colsum = 0.0f, colsq = 0.0f;
    #pragma unroll
    for (int q = 0; q < 4; ++q) {
      int row = mbase + (lane >> 4) * 4 + q;
      float v = acc2[t][q] + bias;
      bool ok = (row < N_NODES) && (j < HDIM);
      if (ok) z[(size_t)row * HDIM + j] = v;
      float sv = ok ? v : 0.0f;
      colsum += sv; colsq += sv * sv;
    }
    colsum += __shfl_xor(colsum, 16);
    colsum += __shfl_xor(colsum, 32);
    colsq  += __shfl_xor(colsq, 16);
    colsq  += __shfl_xor(colsq, 32);
    if (lane < 16 && j < HDIM) {
      atomicAdd(&bn_sum[j], colsum);
      atomicAdd(&bn_sq[j], colsq);
    }
  }
}

__global__ void k_bn_final(const float* __restrict__ bn_sum, const float* __restrict__ bn_sq,
                           float* __restrict__ bn_mu, float* __restrict__ bn_rs) {
  int j = threadIdx.x;
  if (j >= HDIM) return;
  float mu = bn_sum[j] / (float)N_NODES;
  float var = bn_sq[j] / (float)N_NODES - mu * mu;
  bn_mu[j] = mu;
  bn_rs[j] = rsqrtf(var + 1e-5f);
}

// fused h-update + PQt GEMM
__global__ __launch_bounds__(256) void k_h_pq(
    float* h, const float* z,
    const float* __restrict__ bn_mu, const float* __restrict__ bn_rs,
    const float* __restrict__ gamma, const float* __restrict__ beta,
    const _Float16* __restrict__ fb, _Float16* __restrict__ PQt) {
  int lane = threadIdx.x & 63;
  int wave = threadIdx.x >> 6;
  int c = lane & 15, g = lane >> 4;
  int mbase = (blockIdx.x * 4 + wave) * 16;
  int row = mbase + c;
  bool rv = row < N_NODES;
  float* hp = h + (size_t)row * HDIM;
  const float* zp = z + (size_t)row * HDIM;

  half8_t av[4];
  #pragma unroll
  for (int s = 0; s < 4; ++s) {
    int kb = s * 32 + g * 8;
    half8_t a = h8_zero();
    if (rv && kb < HDIM) {
      int lim = (kb + 8 <= HDIM) ? 8 : 4;
      float zf[8], hf[8], mu[8], rs[8], ga[8], be[8];
      { float4 v = *(const float4*)(zp + kb);
        zf[0]=v.x; zf[1]=v.y; zf[2]=v.z; zf[3]=v.w; }
      { float4 v = *(const float4*)(hp + kb);
        hf[0]=v.x; hf[1]=v.y; hf[2]=v.z; hf[3]=v.w; }
      { float4 v = *(const float4*)(bn_mu + kb);
        mu[0]=v.x; mu[1]=v.y; mu[2]=v.z; mu[3]=v.w; }
      { float4 v = *(const float4*)(bn_rs + kb);
        rs[0]=v.x; rs[1]=v.y; rs[2]=v.z; rs[3]=v.w; }
      { float4 v = *(const float4*)(gamma + kb);
        ga[0]=v.x; ga[1]=v.y; ga[2]=v.z; ga[3]=v.w; }
      { float4 v = *(const float4*)(beta + kb);
        be[0]=v.x; be[1]=v.y; be[2]=v.z; be[3]=v.w; }
      if (lim == 8) {
        { float4 v = *(const float4*)(zp + kb + 4);
          zf[4]=v.x; zf[5]=v.y; zf[6]=v.z; zf[7]=v.w; }
        { float4 v = *(const float4*)(hp + kb + 4);
          hf[4]=v.x; hf[5]=v.y; hf[6]=v.z; hf[7]=v.w; }
        { float4 v = *(const float4*)(bn_mu + kb + 4);
          mu[4]=v.x; mu[5]=v.y; mu[6]=v.z; mu[7]=v.w; }
        { float4 v = *(const float4*)(bn_rs + kb + 4);
          rs[4]=v.x; rs[5]=v.y; rs[6]=v.z; rs[7]=v.w; }
        { float4 v = *(const float4*)(gamma + kb + 4);
          ga[4]=v.x; ga[5]=v.y; ga[6]=v.z; ga[7]=v.w; }
        { float4 v = *(const float4*)(beta + kb + 4);
          be[4]=v.x; be[5]=v.y; be[6]=v.z; be[7]=v.w; }
      }
      float hn[8];
      #pragma unroll
      for (int i = 0; i < 8; ++i) hn[i] = 0.0f;
      for (int i = 0; i < 8; ++i) {
        if (i < lim) {
          float zn = (zf[i] - mu[i]) * rs[i] * ga[i] + be[i];
          hn[i] = 0.5f * (hf[i] + fmaxf(zn, 0.0f));
          a[i] = (_Float16)hn[i];
        }
      }
      { float4 v; v.x=hn[0]; v.y=hn[1]; v.z=hn[2]; v.w=hn[3];
        *(float4*)(hp + kb) = v; }
      if (lim == 8) {
        float4 v; v.x=hn[4]; v.y=hn[5]; v.z=hn[6]; v.w=hn[7];
        *(float4*)(hp + kb + 4) = v;
      }
    }
    av[s] = a;
  }

  f32x4_t acc[14];
  #pragma unroll
  for (int t = 0; t < 14; ++t) acc[t] = (f32x4_t){0.f, 0.f, 0.f, 0.f};
  mfma_tiles<14, 4>(av, fb, lane, acc);
  #pragma unroll
  for (int q = 0; q < 4; ++q) {
    int orow = mbase + (lane >> 4) * 4 + q;
    if (orow >= N_NODES) continue;
    half8_t hp8, hq8;
    #pragma unroll
    for (int t = 0; t < 8; ++t) {
      hp8[t] = (t < 7) ? (_Float16)acc[t][q] : (_Float16)0.0f;
      hq8[t] = (t < 7) ? (_Float16)acc[7 + t][q] : (_Float16)0.0f;
    }
    *(half8_t*)(PQt + (size_t)orow * 256 + c * 8) = hp8;
    *(half8_t*)(PQt + (size_t)orow * 256 + 128 + c * 8) = hq8;
  }
}

// RS' GEMM (reads h, relu'd): RS' [node][128]: R slot c*4+t, S slot 64+c*4+t
__global__ __launch_bounds__(256) void k_node_rs(const float* __restrict__ h,
                                                 const _Float16* __restrict__ fb,
                                                 _Float16* __restrict__ out) {
  int lane = threadIdx.x & 63;
  int wave = threadIdx.x >> 6;
  int c = lane & 15;
  int mbase = (blockIdx.x * 4 + wave) * 16;
  half8_t av[4];
  load_a_node<1>(h, h, mbase + c, lane, av);
  f32x4_t acc[8];
  #pragma unroll
  for (int t = 0; t < 8; ++t) acc[t] = (f32x4_t){0.f, 0.f, 0.f, 0.f};
  mfma_tiles<8, 4>(av, fb, lane, acc);
  #pragma unroll
  for (int q = 0; q < 4; ++q) {
    int row = mbase + (lane >> 4) * 4 + q;
    if (row >= N_NODES) continue;
    half4_t hr, hs;
    #pragma unroll
    for (int t = 0; t < 4; ++t) {
      hr[t] = (_Float16)acc[t][q];
      hs[t] = (_Float16)acc[4 + t][q];
    }
    *(half4_t*)(out + (size_t)row * 128 + c * 4) = hr;
    *(half4_t*)(out + (size_t)row * 128 + 64 + c * 4) = hs;
  }
}

// ---------------- layer-0 edge kernel (pos-ordered; e0 never in HBM) ----------------
// Register diet: P/Q gathered AFTER stage-1 MFMA in two half4 phases; e0 carry
// packed as half4 (bit-identical values). No forced launch bound (no spill risk).
__global__ __launch_bounds__(256) void k_edge0(
    const float* __restrict__ attr,
    const _Float16* __restrict__ PQ,
    const int* __restrict__ srcS, const int* __restrict__ dstS,
    const int* __restrict__ perm,
    const float* __restrict__ ew, const float* __restrict__ ebias,
    const _Float16* __restrict__ fbW1c, const _Float16* __restrict__ fbW2,
    const float* __restrict__ b1, const float* __restrict__ b2,
    _Float16* __restrict__ e) {
  __shared__ __align__(16) _Float16 lds[4][2048];
  __shared__ float EwL[800];
  __shared__ float ebL[112];
  int tid = threadIdx.x;
  for (int idx = tid; idx < 800; idx += 256) EwL[idx] = ew[idx];
  if (tid < 112) ebL[tid] = (tid < HDIM) ? ebias[tid] : 0.0f;
  __syncthreads();

  int lane = tid & 63;
  int wave = tid >> 6;
  _Float16* L = lds[wave];
  int mbase = (blockIdx.x * 4 + wave) * 16;
  int c = lane & 15, g = lane >> 4;

  int sn[4], dn[4], pv[4];
  #pragma unroll
  for (int q = 0; q < 4; ++q) {
    int row = mbase + g * 4 + q;
    sn[q] = srcS[row]; dn[q] = dstS[row]; pv[q] = perm[row];
  }

  // attr rows (gathered via perm)
  float af[4][8];
  #pragma unroll
  for (int q = 0; q < 4; ++q) {
    const float* ap = attr + (size_t)pv[q] * 8;
    float4 a0 = *(const float4*)ap;
    float4 a1 = *(const float4*)(ap + 4);
    af[q][0] = a0.x; af[q][1] = a0.y; af[q][2] = a0.z; af[q][3] = a0.w;
    af[q][4] = a1.x; af[q][5] = a1.y; af[q][6] = a1.z; af[q][7] = a1.w;
  }

  // e0 in f32 (same FMA order as original embed_e) -> packed f16 carry + LDS tile
  half4_t e0p[7];
  #pragma unroll
  for (int t = 0; t < 7; ++t) {
    int j = t * 16 + c;
    #pragma unroll
    for (int q = 0; q < 4; ++q) {
      float v = 0.0f;
      if (j < HDIM) {
        v = ebL[j];
        #pragma unroll
        for (int k = 0; k < 8; ++k) v += af[q][k] * EwL[k * HDIM + j];
      }
      _Float16 vh = (_Float16)v;
      e0p[t][q] = vh;
      L[swz_idx(g * 4 + q, j)] = vh;
    }
  }
  { int r = lane >> 2; int c0 = 112 + (lane & 3) * 4;
    #pragma unroll
    for (int i = 0; i < 4; ++i) L[swz_idx(r, c0 + i)] = (_Float16)0.0f;
  }
  __builtin_amdgcn_sched_barrier(0);

  half8_t av[4];
  lds_read_a<4>(L, lane, av);
  __builtin_amdgcn_sched_barrier(0);
  f32x4_t acc[7];
  #pragma unroll
  for (int t = 0; t < 7; ++t) acc[t] = (f32x4_t){0.f, 0.f, 0.f, 0.f};
  mfma_tiles<7, 4>(av, fbW1c, lane, acc);
  __builtin_amdgcn_sched_barrier(0);

  // epilogue 1, phase A: gather P/Q halves for t=0..3, write u1 cols 0..63
  {
    half4_t Pa[4], Qa[4];
    #pragma unroll
    for (int q = 0; q < 4; ++q) {
      Pa[q] = *(const half4_t*)(PQ + (size_t)sn[q] * 256 + c * 8);
      Qa[q] = *(const half4_t*)(PQ + (size_t)dn[q] * 256 + 128 + c * 8);
    }
    #pragma unroll
    for (int t = 0; t < 4; ++t) {
      int j = t * 16 + c;
      float bias = b1[j];
      #pragma unroll
      for (int q = 0; q < 4; ++q) {
        int r = g * 4 + q;
        float v = fmaxf(acc[t][q] + bias + (float)Pa[q][t] + (float)Qa[q][t], 0.0f);
        L[swz_idx(r, j)] = (_Float16)v;
      }
    }
  }
  // epilogue 1, phase B: t=4..6
  {
    half4_t Pb[4], Qb[4];
    #pragma unroll
    for (int q = 0; q < 4; ++q) {
      Pb[q] = *(const half4_t*)(PQ + (size_t)sn[q] * 256 + c * 8 + 4);
      Qb[q] = *(const half4_t*)(PQ + (size_t)dn[q] * 256 + 128 + c * 8 + 4);
    }
    #pragma unroll
    for (int t = 4; t < 7; ++t) {
      int j = t * 16 + c;
      float bias = (j < HDIM) ? b1[j] : 0.0f;
      #pragma unroll
      for (int q = 0; q < 4; ++q) {
        int r = g * 4 + q;
        float v = 0.0f;
        if (j < HDIM)
          v = fmaxf(acc[t][q] + bias + (float)Pb[q][t - 4] + (float)Qb[q][t - 4], 0.0f);
        L[swz_idx(r, j)] = (_Float16)v;
      }
    }
  }
  __builtin_amdgcn_sched_barrier(0);

  half8_t av2[4];
  lds_read_a<4>(L, lane, av2);
  f32x4_t acc2[7];
  #pragma unroll
  for (int t = 0; t < 7; ++t) acc2[t] = (f32x4_t){0.f, 0.f, 0.f, 0.f};
  mfma_tiles<7, 4>(av2, fbW2, lane, acc2);
  __builtin_amdgcn_sched_barrier(0);

  #pragma unroll
  for (int t = 0; t < 7; ++t) {
    int j = t * 16 + c;
    float b2v = (j < HDIM) ? b2[j] : 0.0f;
    #pragma unroll
    for (int q = 0; q < 4; ++q) {
      int row = mbase + g * 4 + q;
      float eold = (float)e0p[t][q];
      float enew = eold + 0.5f * (acc2[t][q] + b2v);
      if (j < ESTR)
        e[(size_t)row * ESTR + j] = (j < HDIM) ? (_Float16)enew : (_Float16)0.0f;
    }
  }
}

// ---------------- layer-1 edge kernel + fused classifier (pos-ordered) ----------------
// Register diet: P/Q gathered AFTER stage-1 MFMA (two half4 phases); R/S after
// classifier stage-1 MFMA. No forced launch bound.
__global__ __launch_bounds__(256) void k_edge1(
    const _Float16* __restrict__ e,
    const _Float16* __restrict__ PQ, const _Float16* __restrict__ RS,
    const int* __restrict__ srcS, const int* __restrict__ dstS,
    const int* __restrict__ perm,
    const _Float16* __restrict__ fbW1c, const _Float16* __restrict__ fbW2,
    const float* __restrict__ b1, const float* __restrict__ b2,
    const _Float16* __restrict__ fbC, const _Float16* __restrict__ fbM2,
    const _Float16* __restrict__ fbM3,
    const float* __restrict__ mb1, const float* __restrict__ mb2,
    const float* __restrict__ mb3, float* __restrict__ out) {
  __shared__ __align__(16) _Float16 lds[4][2048];
  int lane = threadIdx.x & 63;
  int wave = threadIdx.x >> 6;
  _Float16* L = lds[wave];
  int mbase = (blockIdx.x * 4 + wave) * 16;
  int c = lane & 15, g = lane >> 4;

  // e A-loads issued first (streaming, independent of indices)
  half8_t av[4];
  {
    const _Float16* ep = e + (size_t)(mbase + c) * ESTR;
    #pragma unroll
    for (int s = 0; s < 3; ++s)
      av[s] = *(const half8_t*)(ep + s * 32 + g * 8);
    av[3] = (g == 0) ? *(const half8_t*)(ep + 96) : h8_zero();
  }

  int sn[4], dn[4];
  #pragma unroll
  for (int q = 0; q < 4; ++q) {
    int row = mbase + g * 4 + q;
    sn[q] = srcS[row]; dn[q] = dstS[row];
  }

  f32x4_t acc[7];
  #pragma unroll
  for (int t = 0; t < 7; ++t) acc[t] = (f32x4_t){0.f, 0.f, 0.f, 0.f};
  mfma_tiles<7, 4>(av, fbW1c, lane, acc);
  __builtin_amdgcn_sched_barrier(0);

  // epilogue 1, phase A: gather P/Q halves for t=0..3 (post-MFMA; only 16 VGPR live)
  {
    half4_t Pa[4], Qa[4];
    #pragma unroll
    for (int q = 0; q < 4; ++q) {
      Pa[q] = *(const half4_t*)(PQ + (size_t)sn[q] * 256 + c * 8);
      Qa[q] = *(const half4_t*)(PQ + (size_t)dn[q] * 256 + 128 + c * 8);
    }
    #pragma unroll
    for (int t = 0; t < 4; ++t) {
      int j = t * 16 + c;
      float bias = b1[j];
      #pragma unroll
      for (int q = 0; q < 4; ++q) {
        int r = g * 4 + q;
        float v = fmaxf(acc[t][q] + bias + (float)Pa[q][t] + (float)Qa[q][t], 0.0f);
        L[swz_idx(r, j)] = (_Float16)v;
      }
    }
  }
  // epilogue 1, phase B: t=4..6
  {
    half4_t Pb[4], Qb[4];
    #pragma unroll
    for (int q = 0; q < 4; ++q) {
      Pb[q] = *(const half4_t*)(PQ + (size_t)sn[q] * 256 + c * 8 + 4);
      Qb[q] = *(const half4_t*)(PQ + (size_t)dn[q] * 256 + 128 + c * 8 + 4);
    }
    #pragma unroll
    for (int t = 4; t < 7; ++t) {
      int j = t * 16 + c;
      float bias = (j < HDIM) ? b1[j] : 0.0f;
      #pragma unroll
      for (int q = 0; q < 4; ++q) {
        int r = g * 4 + q;
        float v = 0.0f;
        if (j < HDIM)
          v = fmaxf(acc[t][q] + bias + (float)Pb[q][t - 4] + (float)Qb[q][t - 4], 0.0f);
        L[swz_idx(r, j)] = (_Float16)v;
      }
    }
  }
  { int r = lane >> 2; int c0 = 112 + (lane & 3) * 4;
    #pragma unroll
    for (int i = 0; i < 4; ++i) L[swz_idx(r, c0 + i)] = (_Float16)0.0f;
  }
  __builtin_amdgcn_sched_barrier(0);

  half8_t av2[4];
  lds_read_a<4>(L, lane, av2);
  f32x4_t acc2[7];
  #pragma unroll
  for (int t = 0; t < 7; ++t) acc2[t] = (f32x4_t){0.f, 0.f, 0.f, 0.f};
  mfma_tiles<7, 4>(av2, fbW2, lane, acc2);
  __builtin_amdgcn_sched_barrier(0);

  // epilogue 2: e2 -> LDS; eold via global re-read (L2-hot from stage 1)
  #pragma unroll
  for (int t = 0; t < 7; ++t) {
    int j = t * 16 + c;
    float bias = (j < HDIM) ? b2[j] : 0.0f;
    #pragma unroll
    for (int q = 0; q < 4; ++q) {
      int row = mbase + g * 4 + q;
      float v = 0.0f;
      if (j < HDIM) {
        float eold = (float)e[(size_t)row * ESTR + j];
        v = eold + 0.5f * (acc2[t][q] + bias);
      }
      int r = g * 4 + q;
      L[swz_idx(r, j)] = (_Float16)v;
    }
  }
  __builtin_amdgcn_sched_barrier(0);

  // classifier stage 1: t1 = relu(e2@C + R + S + mb1), 50 outs
  half8_t av3[4];
  lds_read_a<4>(L, lane, av3);
  f32x4_t acc3[4];
  #pragma unroll
  for (int t = 0; t < 4; ++t) acc3[t] = (f32x4_t){0.f, 0.f, 0.f, 0.f};
  mfma_tiles<4, 4>(av3, fbC, lane, acc3);
  __builtin_amdgcn_sched_barrier(0);
  // R/S gathers post-MFMA (short live range)
  {
    half4_t Rf[4], Sf[4];
    #pragma unroll
    for (int q = 0; q < 4; ++q) {
      Rf[q] = *(const half4_t*)(RS + (size_t)sn[q] * 128 + c * 4);
      Sf[q] = *(const half4_t*)(RS + (size_t)dn[q] * 128 + 64 + c * 4);
    }
    #pragma unroll
    for (int t = 0; t < 4; ++t) {
      int j = t * 16 + c;
      float bias = (j < 50) ? mb1[j] : 0.0f;
      #pragma unroll
      for (int q = 0; q < 4; ++q) {
        float v = 0.0f;
        if (j < 50)
          v = fmaxf(acc3[t][q] + bias + (float)Rf[q][t] + (float)Sf[q][t], 0.0f);
        int r = g * 4 + q;
        L[swz_idx(r, j)] = (_Float16)v;
      }
    }
  }
  __builtin_amdgcn_sched_barrier(0);
  // classifier stage 2: t2 = relu(t1@M2 + mb2), 25 outs
  half8_t av4[2];
  lds_read_a<2>(L, lane, av4);
  f32x4_t acc4[2];
  #pragma unroll
  for (int t = 0; t < 2; ++t) acc4[t] = (f32x4_t){0.f, 0.f, 0.f, 0.f};
  mfma_tiles<2, 2>(av4, fbM2, lane, acc4);
  __builtin_amdgcn_sched_barrier(0);
  #pragma unroll
  for (int t = 0; t < 2; ++t) {
    int j = t * 16 + c;
    float bias = (j < 25) ? mb2[j] : 0.0f;
    #pragma unroll
    for (int q = 0; q < 4; ++q) {
      float v = (j < 25) ? fmaxf(acc4[t][q] + bias, 0.0f) : 0.0f;
      int r = g * 4 + q;
      L[swz_idx(r, j)] = (_Float16)v;
    }
  }
  __builtin_amdgcn_sched_barrier(0);
  // classifier stage 3: out = t2@M3 + mb3 (scattered to original edge ids)
  half8_t av5[1];
  lds_read_a<1>(L, lane, av5);
  f32x4_t acc5 = (f32x4_t){0.f, 0.f, 0.f, 0.f};
  {
    half8_t bv = *(const half8_t*)(fbM3 + (size_t)(lane << 3));
    acc5 = __builtin_amdgcn_mfma_f32_16x16x32_f16(av5[0], bv, acc5, 0, 0, 0);
  }
  if (c < 2) {
    float bias = mb3[c];
    #pragma unroll
    for (int q = 0; q < 4; ++q) {
      int row = mbase + g * 4 + q;
      out[(size_t)perm[row] * 2 + c] = acc5[q] + bias;
    }
  }
}

// ---------------- host launch ----------------
extern "C" void kernel_launch(void* const* d_in, const int* in_sizes, int n_in,
                              void* d_out, int out_size, void* d_ws, size_t ws_size,
                              hipStream_t stream) {
  const float* x        = (const float*)d_in[0];
  const int*   ei       = (const int*)  d_in[1];
  const float* eattr    = (const float*)d_in[2];
  const float* node_w   = (const float*)d_in[3];
  const float* node_b   = (const float*)d_in[4];
  const float* edge_w   = (const float*)d_in[5];
  const float* edge_b   = (const float*)d_in[6];
  const float* conv_w1  = (const float*)d_in[7];
  const float* conv_b1  = (const float*)d_in[8];
  const float* conv_w2  = (const float*)d_in[9];
  const float* conv_b2  = (const float*)d_in[10];
  const float* bn_gamma = (const float*)d_in[11];
  const float* bn_beta  = (const float*)d_in[12];
  const float* emlp_w1  = (const float*)d_in[13];
  const float* emlp_b1  = (const float*)d_in[14];
  const float* emlp_w2  = (const float*)d_in[15];
  const float* emlp_b2  = (const float*)d_in[16];
  const float* mlp_w1   = (const float*)d_in[17];
  const float* mlp_b1   = (const float*)d_in[18];
  const float* mlp_w2   = (const float*)d_in[19];
  const float* mlp_b2   = (const float*)d_in[20];
  const float* mlp_w3   = (const float*)d_in[21];
  const float* mlp_b3   = (const float*)d_in[22];
  const int* src = ei;
  const int* dst = ei + N_EDGES;

  char* ws = (char*)d_ws;
  size_t off = 0;
  auto alloc = [&](size_t bytes) -> void* {
    void* p = ws + off;
    off += (bytes + 255) & ~(size_t)255;
    return p;
  };
  _Float16* e    = (_Float16*)alloc((size_t)N_EDGES * ESTR * 2);   // 166.4 MB (pos order)
  float* h       = (float*)alloc((size_t)N_NODES * HDIM * 4);      //  20 MB
  float* agg     = (float*)alloc((size_t)N_NODES * HDIM * 4);      //  20 MB (z, RSt alias)
  _Float16* PQt  = (_Float16*)alloc((size_t)N_NODES * 256 * 2);    //  25.6 MB
  int* cursor    = (int*)alloc((size_t)N_NODES * 4);               //  0.2 MB (doubles as hist)
  int* rowptr    = (int*)alloc((size_t)(N_NODES + 1) * 4);         //  0.2 MB
  int* perm      = (int*)alloc((size_t)N_EDGES * 4);               //  3.2 MB
  int* srcS      = (int*)alloc((size_t)N_EDGES * 4);               //  3.2 MB
  int* dstS      = (int*)alloc((size_t)N_EDGES * 4);               //  3.2 MB
  float* bn_sum  = (float*)alloc(512);
  float* bn_sq   = (float*)alloc(512);
  float* bn_mu   = (float*)alloc(512);
  float* bn_rs   = (float*)alloc(512);
  _Float16* frags = (_Float16*)alloc(200000 * 2);                  //  0.4 MB
  float* z = agg;                 // alias: conv reads agg rows before writing same z rows
  _Float16* RSt = (_Float16*)agg; // alias: written at i==1 after z is dead

  if (off > ws_size) {
    k_ws_probe<<<1, 1, 0, stream>>>((float*)d_out, (float)(ws_size >> 20));
    return;
  }

  // fragment descriptor table
  PrepArgs pa;
  int nd = 0, tilesum = 0, fo = 0;
  auto add = [&](const float* sp, int stride, int K, int Ncols, int ksteps, int ntiles) -> int {
    pa.d[nd] = FragDesc{sp, stride, K, Ncols, fo, ksteps, ntiles};
    pa.prefix[nd] = tilesum;
    tilesum += ksteps * ntiles;
    ++nd;
    int ret = fo;
    fo += ksteps * ntiles * 512;
    return ret;
  };
  int offConvW1[2], offConvW2[2], offPQ[2], offW1c[2], offW2e[2];
  for (int i = 0; i < 2; ++i) {
    offConvW1[i] = add(conv_w1 + i * 10000, 100, 100, 100, 4, 7);
    offConvW2[i] = add(conv_w2 + i * 10000, 100, 100, 100, 4, 7);
    offPQ[i]     = add(emlp_w1 + i * 30000,         100, 100, 100, 4, 7);  // W1a (P)
                   add(emlp_w1 + i * 30000 + 10000, 100, 100, 100, 4, 7);  // W1b (Q), contiguous
    offW1c[i]    = add(emlp_w1 + i * 30000 + 20000, 100, 100, 100, 4, 7);
    offW2e[i]    = add(emlp_w2 + i * 10000, 100, 100, 100, 4, 7);
  }
  int offRS = add(mlp_w1,         50, 100, 50, 4, 4);   // R
              add(mlp_w1 + 5000,  50, 100, 50, 4, 4);   // S, contiguous
  int offC  = add(mlp_w1 + 10000, 50, 100, 50, 4, 4);
  int offM2 = add(mlp_w2, 25, 50, 25, 2, 2);
  int offM3 = add(mlp_w3, 2, 25, 2, 1, 1);
  pa.prefix[nd] = tilesum;
  pa.ndesc = nd;

  // CSR build (dst layer-invariant: one sort serves both layers)
  hipMemsetAsync(cursor, 0, (size_t)N_NODES * 4, stream);
  k_hist<<<2048, 256, 0, stream>>>(dst, cursor);
  k_scan<<<1, 1024, 0, stream>>>(cursor, rowptr, cursor);
  k_perm<<<2048, 256, 0, stream>>>(src, dst, cursor, perm, srcS, dstS);

  k_prep_frags<<<tilesum, 64, 0, stream>>>(pa, frags);
  k_embed_h<<<N_NODES, 128, 0, stream>>>(x, node_w, node_b, h);
  // layer-0 aggregation: gather, e0 recomputed in exact f32
  k_agg<true><<<N_NODES / 2, 256, 0, stream>>>(rowptr, perm, srcS,
                                               eattr, edge_w, edge_b,
                                               nullptr, h, agg);

  const int nodeGrid = (N_NODES + 63) / 64;  // 782
  for (int i = 0; i < 2; ++i) {
    hipMemsetAsync(bn_sum, 0, 512, stream);
    hipMemsetAsync(bn_sq, 0, 512, stream);
    k_node_conv<<<nodeGrid, 256, 0, stream>>>(h, agg, frags + offConvW1[i], frags + offConvW2[i],
                                              conv_b1 + i * 100, conv_b2 + i * 100,
                                              z, bn_sum, bn_sq);
    k_bn_final<<<1, 128, 0, stream>>>(bn_sum, bn_sq, bn_mu, bn_rs);
    // fused h-update + PQ' GEMM
    k_h_pq<<<nodeGrid, 256, 0, stream>>>(h, z, bn_mu, bn_rs,
                                         bn_gamma + i * 100, bn_beta + i * 100,
                                         frags + offPQ[i], PQt);
    if (i == 0) {
      k_edge0<<<N_EDGES / 64, 256, 0, stream>>>(
          eattr, PQt, srcS, dstS, perm, edge_w, edge_b,
          frags + offW1c[0], frags + offW2e[0],
          emlp_b1, emlp_b2, e);
      // layer-1 aggregation: e is pos-ordered -> sequential reads
      k_agg<false><<<N_NODES / 2, 256, 0, stream>>>(rowptr, perm, srcS,
                                                    nullptr, nullptr, nullptr,
                                                    e, h, agg);
    } else {
      k_node_rs<<<nodeGrid, 256, 0, stream>>>(h, frags + offRS, RSt);
      k_edge1<<<N_EDGES / 64, 256, 0, stream>>>(
          e, PQt, RSt, srcS, dstS, perm,
          frags + offW1c[1], frags + offW2e[1],
          emlp_b1 + 100, emlp_b2 + 100,
          frags + offC, frags + offM2, frags + offM3,
          mlp_b1, mlp_b2, mlp_b3, (float*)d_out);
    }
  }
}